// Round 2
// baseline (21058.595 us; speedup 1.0000x reference)
//
#include <hip/hip_runtime.h>
#include <hip/hip_bf16.h>
#include <math.h>

// ---------------- GEMM: Hout[n][m] = sum_k X[n][k] * W[k][m] ----------------
template<int K, int M>
__global__ __launch_bounds__(256) void gemm_kernel(
    const float* __restrict__ X, const float* __restrict__ W,
    float* __restrict__ Hout, int N)
{
    int gid = blockIdx.x * 256 + threadIdx.x;
    if (gid >= N * M) return;
    int n = gid / M;
    int m = gid - n * M;
    const float* xr = X + (size_t)n * K;
    float acc = 0.f;
    #pragma unroll 8
    for (int k = 0; k < K; ++k)
        acc += xr[k] * W[k * M + m];
    Hout[gid] = acc;
}

// ---------------- alpha_src/alpha_dst: [N,H] = sum_f h[n,hd,f]*a[hd,f] ------
template<int H, int F>
__global__ __launch_bounds__(256) void alpha_kernel(
    const float* __restrict__ h, const float* __restrict__ av_src,
    const float* __restrict__ av_dst, float* __restrict__ asrc,
    float* __restrict__ adst, int N)
{
    int gid = blockIdx.x * 256 + threadIdx.x;
    if (gid >= N * H) return;
    int n = gid / H;
    int hd = gid - n * H;
    const float* hr = h + (size_t)n * (H * F) + hd * F;
    float s1 = 0.f, s2 = 0.f;
    #pragma unroll
    for (int f = 0; f < F; ++f) {
        float v = hr[f];
        s1 += v * av_src[hd * F + f];
        s2 += v * av_dst[hd * F + f];
    }
    asrc[gid] = s1;
    adst[gid] = s2;
}

// ---------------- edge pass A: softmax denominators -------------------------
template<int H>
__global__ __launch_bounds__(256) void denom_kernel(
    const int* __restrict__ ei, int E, int N,
    const float* __restrict__ asrc, const float* __restrict__ adst,
    float* __restrict__ sden)
{
    int i = blockIdx.x * 256 + threadIdx.x;
    int ET = E + N;
    if (i >= ET) return;
    int src, dst;
    if (i < E) { src = ei[i]; dst = ei[E + i]; }
    else       { src = dst = i - E; }
    #pragma unroll
    for (int hd = 0; hd < H; ++hd) {
        float e = asrc[src * H + hd] + adst[dst * H + hd];
        e = e > 0.f ? e : 0.2f * e;
        atomicAdd(&sden[dst * H + hd], __expf(e));
    }
}

// ---------------- edge pass B: out[dst] += h[src] * exp(e)/s[dst] -----------
template<int H, int F>
__global__ __launch_bounds__(256) void agg_kernel(
    const int* __restrict__ ei, int E, int N,
    const float* __restrict__ asrc, const float* __restrict__ adst,
    const float* __restrict__ sden, const float* __restrict__ h,
    float* __restrict__ out)
{
    long tid = (long)blockIdx.x * 256 + threadIdx.x;
    int ET = E + N;
    if (tid >= (long)ET * H) return;
    int i = (int)(tid / H);
    int hd = (int)(tid - (long)i * H);
    int src, dst;
    if (i < E) { src = ei[i]; dst = ei[E + i]; }
    else       { src = dst = i - E; }
    float e = asrc[src * H + hd] + adst[dst * H + hd];
    e = e > 0.f ? e : 0.2f * e;
    float w = __expf(e) / (sden[dst * H + hd] + 1e-16f);
    const float* hr = h + (size_t)src * (H * F) + hd * F;
    float* orow = out + (size_t)dst * (H * F) + hd * F;
    if constexpr (F % 4 == 0) {
        const float4* h4 = reinterpret_cast<const float4*>(hr);
        #pragma unroll
        for (int f4 = 0; f4 < F / 4; ++f4) {
            float4 v = h4[f4];
            atomicAdd(&orow[f4 * 4 + 0], v.x * w);
            atomicAdd(&orow[f4 * 4 + 1], v.y * w);
            atomicAdd(&orow[f4 * 4 + 2], v.z * w);
            atomicAdd(&orow[f4 * 4 + 3], v.w * w);
        }
    } else {
        #pragma unroll
        for (int f = 0; f < F; ++f)
            atomicAdd(&orow[f], hr[f] * w);
    }
}

// ---------------- bias + LayerNorm + ELU (one wave per node) ----------------
template<int M>
__global__ __launch_bounds__(256) void ln_elu_kernel(
    float* __restrict__ x, const float* __restrict__ bias,
    const float* __restrict__ g, const float* __restrict__ be, int N)
{
    int n = blockIdx.x * 4 + (threadIdx.x >> 6);
    int lane = threadIdx.x & 63;
    if (n >= N) return;
    float* row = x + (size_t)n * M;
    constexpr int PER = M / 64;
    float v[PER];
    float sum = 0.f;
    #pragma unroll
    for (int p = 0; p < PER; ++p) {
        int m = lane + p * 64;
        v[p] = row[m] + bias[m];
        sum += v[p];
    }
    #pragma unroll
    for (int o = 32; o >= 1; o >>= 1) sum += __shfl_xor(sum, o, 64);
    float mu = sum * (1.0f / M);
    float vs = 0.f;
    #pragma unroll
    for (int p = 0; p < PER; ++p) { float d = v[p] - mu; vs += d * d; }
    #pragma unroll
    for (int o = 32; o >= 1; o >>= 1) vs += __shfl_xor(vs, o, 64);
    float inv = rsqrtf(vs * (1.0f / M) + 1e-5f);
    #pragma unroll
    for (int p = 0; p < PER; ++p) {
        int m = lane + p * 64;
        float y = (v[p] - mu) * inv * g[m] + be[m];
        y = y > 0.f ? y : expm1f(y);
        row[m] = y;
    }
}

// ---------------- final: +bias then log_softmax over 10, write fp32 ---------
__global__ __launch_bounds__(256) void final_kernel(
    const float* __restrict__ agg, const float* __restrict__ b3,
    float* __restrict__ out, int N)
{
    int n = blockIdx.x * 256 + threadIdx.x;
    if (n >= N) return;
    float v[10];
    float mx = -1e30f;
    #pragma unroll
    for (int j = 0; j < 10; ++j) {
        v[j] = agg[(size_t)n * 10 + j] + b3[j];
        mx = fmaxf(mx, v[j]);
    }
    float se = 0.f;
    #pragma unroll
    for (int j = 0; j < 10; ++j) se += __expf(v[j] - mx);
    float ls = mx + logf(se);
    #pragma unroll
    for (int j = 0; j < 10; ++j)
        out[(size_t)n * 10 + j] = v[j] - ls;
}

static inline int cdiv(long a, long b) { return (int)((a + b - 1) / b); }

extern "C" void kernel_launch(void* const* d_in, const int* in_sizes, int n_in,
                              void* d_out, int out_size, void* d_ws, size_t ws_size,
                              hipStream_t stream)
{
    const float* x   = (const float*)d_in[0];
    const int*   ei  = (const int*)d_in[1];
    const float* W1  = (const float*)d_in[2];
    const float* as1 = (const float*)d_in[3];
    const float* ad1 = (const float*)d_in[4];
    const float* b1  = (const float*)d_in[5];
    const float* g1  = (const float*)d_in[6];
    const float* be1 = (const float*)d_in[7];
    const float* W2  = (const float*)d_in[8];
    const float* as2 = (const float*)d_in[9];
    const float* ad2 = (const float*)d_in[10];
    const float* b2  = (const float*)d_in[11];
    const float* g2  = (const float*)d_in[12];
    const float* be2 = (const float*)d_in[13];
    const float* W3  = (const float*)d_in[14];
    const float* as3 = (const float*)d_in[15];
    const float* ad3 = (const float*)d_in[16];
    const float* b3  = (const float*)d_in[17];

    const int N = in_sizes[0] / 128;
    const int E = in_sizes[1] / 2;

    float* ws   = (float*)d_ws;
    float* h    = ws;                        // N*128 max
    float* agg  = h + (size_t)N * 128;       // N*128 max
    float* asrc = agg + (size_t)N * 128;     // N*8 max
    float* adst = asrc + (size_t)N * 8;      // N*8 max
    float* sden = adst + (size_t)N * 8;      // N*8 max

    // ================= layer 1: 128 -> 8 heads x 16 =================
    gemm_kernel<128, 128><<<cdiv((long)N * 128, 256), 256, 0, stream>>>(x, W1, h, N);
    alpha_kernel<8, 16><<<cdiv((long)N * 8, 256), 256, 0, stream>>>(h, as1, ad1, asrc, adst, N);
    hipMemsetAsync(sden, 0, (size_t)N * 8 * sizeof(float), stream);
    hipMemsetAsync(agg, 0, (size_t)N * 128 * sizeof(float), stream);
    denom_kernel<8><<<cdiv(E + N, 256), 256, 0, stream>>>(ei, E, N, asrc, adst, sden);
    agg_kernel<8, 16><<<cdiv((long)(E + N) * 8, 256), 256, 0, stream>>>(ei, E, N, asrc, adst, sden, h, agg);
    ln_elu_kernel<128><<<cdiv(N, 4), 256, 0, stream>>>(agg, b1, g1, be1, N);

    // ================= layer 2: 128 -> 4 heads x 16 =================
    gemm_kernel<128, 64><<<cdiv((long)N * 64, 256), 256, 0, stream>>>(agg, W2, h, N);
    alpha_kernel<4, 16><<<cdiv((long)N * 4, 256), 256, 0, stream>>>(h, as2, ad2, asrc, adst, N);
    hipMemsetAsync(sden, 0, (size_t)N * 4 * sizeof(float), stream);
    hipMemsetAsync(agg, 0, (size_t)N * 64 * sizeof(float), stream);
    denom_kernel<4><<<cdiv(E + N, 256), 256, 0, stream>>>(ei, E, N, asrc, adst, sden);
    agg_kernel<4, 16><<<cdiv((long)(E + N) * 4, 256), 256, 0, stream>>>(ei, E, N, asrc, adst, sden, h, agg);
    ln_elu_kernel<64><<<cdiv(N, 4), 256, 0, stream>>>(agg, b2, g2, be2, N);

    // ================= layer 3: 64 -> 1 head x 10, mean(=identity) ==
    gemm_kernel<64, 10><<<cdiv((long)N * 10, 256), 256, 0, stream>>>(agg, W3, h, N);
    alpha_kernel<1, 10><<<cdiv(N, 256), 256, 0, stream>>>(h, as3, ad3, asrc, adst, N);
    hipMemsetAsync(sden, 0, (size_t)N * sizeof(float), stream);
    hipMemsetAsync(agg, 0, (size_t)N * 10 * sizeof(float), stream);
    denom_kernel<1><<<cdiv(E + N, 256), 256, 0, stream>>>(ei, E, N, asrc, adst, sden);
    agg_kernel<1, 10><<<cdiv(E + N, 256), 256, 0, stream>>>(ei, E, N, asrc, adst, sden, h, agg);
    final_kernel<<<cdiv(N, 256), 256, 0, stream>>>(agg, b3, (float*)d_out, N);
}

// Round 3
// 1823.287 us; speedup vs baseline: 11.5498x; 11.5498x over previous
//
#include <hip/hip_runtime.h>
#include <hip/hip_bf16.h>
#include <math.h>

// ---------------- GEMM: Hout[n][m] = sum_k X[n][k] * W[k][m] ----------------
template<int K, int M>
__global__ __launch_bounds__(256) void gemm_kernel(
    const float* __restrict__ X, const float* __restrict__ W,
    float* __restrict__ Hout, int N)
{
    int gid = blockIdx.x * 256 + threadIdx.x;
    if (gid >= N * M) return;
    int n = gid / M;
    int m = gid - n * M;
    const float* xr = X + (size_t)n * K;
    float acc = 0.f;
    #pragma unroll 8
    for (int k = 0; k < K; ++k)
        acc += xr[k] * W[k * M + m];
    Hout[gid] = acc;
}

// ---------------- alpha_src/alpha_dst: [N,H] = sum_f h[n,hd,f]*a[hd,f] ------
template<int H, int F>
__global__ __launch_bounds__(256) void alpha_kernel(
    const float* __restrict__ h, const float* __restrict__ av_src,
    const float* __restrict__ av_dst, float* __restrict__ asrc,
    float* __restrict__ adst, int N)
{
    int gid = blockIdx.x * 256 + threadIdx.x;
    if (gid >= N * H) return;
    int n = gid / H;
    int hd = gid - n * H;
    const float* hr = h + (size_t)n * (H * F) + hd * F;
    float s1 = 0.f, s2 = 0.f;
    #pragma unroll
    for (int f = 0; f < F; ++f) {
        float v = hr[f];
        s1 += v * av_src[hd * F + f];
        s2 += v * av_dst[hd * F + f];
    }
    asrc[gid] = s1;
    adst[gid] = s2;
}

// ---------------- CSR build: histogram -> scan -> scatter -------------------
__global__ __launch_bounds__(256) void hist_kernel(
    const int* __restrict__ ei, int E, int* __restrict__ ptr)
{
    int i = blockIdx.x * 256 + threadIdx.x;
    if (i >= E) return;
    atomicAdd(&ptr[ei[E + i] + 1], 1);
}

// single-block in-place inclusive scan over n ints
__global__ __launch_bounds__(256) void scan_kernel(int* __restrict__ p, int n)
{
    __shared__ int sm[256];
    int tid = threadIdx.x;
    int carry = 0;
    for (int base = 0; base < n; base += 256) {
        int i = base + tid;
        int v = (i < n) ? p[i] : 0;
        sm[tid] = v;
        __syncthreads();
        #pragma unroll
        for (int o = 1; o < 256; o <<= 1) {
            int t = (tid >= o) ? sm[tid - o] : 0;
            __syncthreads();
            sm[tid] += t;
            __syncthreads();
        }
        if (i < n) p[i] = sm[tid] + carry;
        carry += sm[255];
        __syncthreads();
    }
}

// after scatter, ptr[d] becomes END of node d; start = (d?ptr[d-1]:0)
__global__ __launch_bounds__(256) void scatter_kernel(
    const int* __restrict__ ei, int E, int* __restrict__ ptr,
    int* __restrict__ col)
{
    int i = blockIdx.x * 256 + threadIdx.x;
    if (i >= E) return;
    int src = ei[i];
    int dst = ei[E + i];
    int pos = atomicAdd(&ptr[dst], 1);
    col[pos] = src;
}

// ---------------- CSR aggregation: one block (H*F threads) per dst ----------
// out[d] = (w_self*h[d] + sum_e w_e*h[col[e]]) / (w_self + sum_e w_e)
template<int H, int F>
__global__ __launch_bounds__(H * F) void agg_csr_kernel(
    const int* __restrict__ ptr, const int* __restrict__ col,
    const float* __restrict__ asrc, const float* __restrict__ adst,
    const float* __restrict__ h, float* __restrict__ out, int N)
{
    int d = blockIdx.x;
    int tid = threadIdx.x;
    int hd = tid / F;
    int start = (d == 0) ? 0 : ptr[d - 1];
    int end = ptr[d];
    float adst_h = adst[d * H + hd];
    // self loop
    float lg = asrc[d * H + hd] + adst_h;
    lg = lg > 0.f ? lg : 0.2f * lg;
    float w = __expf(lg);
    float acc = w * h[(size_t)d * (H * F) + tid];
    float den = w;
    for (int e = start; e < end; ++e) {
        int s = col[e];
        float lg2 = asrc[s * H + hd] + adst_h;
        lg2 = lg2 > 0.f ? lg2 : 0.2f * lg2;
        float w2 = __expf(lg2);
        acc += w2 * h[(size_t)s * (H * F) + tid];
        den += w2;
    }
    out[(size_t)d * (H * F) + tid] = acc / (den + 1e-16f);
}

// ---------------- layer-3 aggregation: one wave per dst, H=1, F=10 ----------
__global__ __launch_bounds__(256) void agg_csr_l3(
    const int* __restrict__ ptr, const int* __restrict__ col,
    const float* __restrict__ asrc, const float* __restrict__ adst,
    const float* __restrict__ h, float* __restrict__ out, int N)
{
    int wave = threadIdx.x >> 6;
    int lane = threadIdx.x & 63;
    int d = blockIdx.x * 4 + wave;
    if (d >= N) return;
    int start = (d == 0) ? 0 : ptr[d - 1];
    int end = ptr[d];
    float adst_d = adst[d];
    float lg = asrc[d] + adst_d;
    lg = lg > 0.f ? lg : 0.2f * lg;
    float w = __expf(lg);
    float acc = (lane < 10) ? w * h[(size_t)d * 10 + lane] : 0.f;
    float den = w;
    for (int e = start; e < end; ++e) {
        int s = col[e];
        float lg2 = asrc[s] + adst_d;
        lg2 = lg2 > 0.f ? lg2 : 0.2f * lg2;
        float w2 = __expf(lg2);
        if (lane < 10) acc += w2 * h[(size_t)s * 10 + lane];
        den += w2;
    }
    if (lane < 10) out[(size_t)d * 10 + lane] = acc / (den + 1e-16f);
}

// ---------------- bias + LayerNorm + ELU (one wave per node) ----------------
template<int M>
__global__ __launch_bounds__(256) void ln_elu_kernel(
    float* __restrict__ x, const float* __restrict__ bias,
    const float* __restrict__ g, const float* __restrict__ be, int N)
{
    int n = blockIdx.x * 4 + (threadIdx.x >> 6);
    int lane = threadIdx.x & 63;
    if (n >= N) return;
    float* row = x + (size_t)n * M;
    constexpr int PER = M / 64;
    float v[PER];
    float sum = 0.f;
    #pragma unroll
    for (int p = 0; p < PER; ++p) {
        int m = lane + p * 64;
        v[p] = row[m] + bias[m];
        sum += v[p];
    }
    #pragma unroll
    for (int o = 32; o >= 1; o >>= 1) sum += __shfl_xor(sum, o, 64);
    float mu = sum * (1.0f / M);
    float vs = 0.f;
    #pragma unroll
    for (int p = 0; p < PER; ++p) { float d = v[p] - mu; vs += d * d; }
    #pragma unroll
    for (int o = 32; o >= 1; o >>= 1) vs += __shfl_xor(vs, o, 64);
    float inv = rsqrtf(vs * (1.0f / M) + 1e-5f);
    #pragma unroll
    for (int p = 0; p < PER; ++p) {
        int m = lane + p * 64;
        float y = (v[p] - mu) * inv * g[m] + be[m];
        y = y > 0.f ? y : expm1f(y);
        row[m] = y;
    }
}

// ---------------- final: +bias then log_softmax over 10, write fp32 ---------
__global__ __launch_bounds__(256) void final_kernel(
    const float* __restrict__ agg, const float* __restrict__ b3,
    float* __restrict__ out, int N)
{
    int n = blockIdx.x * 256 + threadIdx.x;
    if (n >= N) return;
    float v[10];
    float mx = -1e30f;
    #pragma unroll
    for (int j = 0; j < 10; ++j) {
        v[j] = agg[(size_t)n * 10 + j] + b3[j];
        mx = fmaxf(mx, v[j]);
    }
    float se = 0.f;
    #pragma unroll
    for (int j = 0; j < 10; ++j) se += __expf(v[j] - mx);
    float ls = mx + logf(se);
    #pragma unroll
    for (int j = 0; j < 10; ++j)
        out[(size_t)n * 10 + j] = v[j] - ls;
}

static inline int cdiv(long a, long b) { return (int)((a + b - 1) / b); }

extern "C" void kernel_launch(void* const* d_in, const int* in_sizes, int n_in,
                              void* d_out, int out_size, void* d_ws, size_t ws_size,
                              hipStream_t stream)
{
    const float* x   = (const float*)d_in[0];
    const int*   ei  = (const int*)d_in[1];
    const float* W1  = (const float*)d_in[2];
    const float* as1 = (const float*)d_in[3];
    const float* ad1 = (const float*)d_in[4];
    const float* b1  = (const float*)d_in[5];
    const float* g1  = (const float*)d_in[6];
    const float* be1 = (const float*)d_in[7];
    const float* W2  = (const float*)d_in[8];
    const float* as2 = (const float*)d_in[9];
    const float* ad2 = (const float*)d_in[10];
    const float* b2  = (const float*)d_in[11];
    const float* g2  = (const float*)d_in[12];
    const float* be2 = (const float*)d_in[13];
    const float* W3  = (const float*)d_in[14];
    const float* as3 = (const float*)d_in[15];
    const float* ad3 = (const float*)d_in[16];
    const float* b3  = (const float*)d_in[17];

    const int N = in_sizes[0] / 128;
    const int E = in_sizes[1] / 2;

    float* h    = (float*)d_ws;              // N*128
    float* agg  = h + (size_t)N * 128;       // N*128
    float* asrc = agg + (size_t)N * 128;     // N*8
    float* adst = asrc + (size_t)N * 8;      // N*8
    int*   ptr  = (int*)(adst + (size_t)N * 8); // N+1
    int*   col  = ptr + (N + 1);             // E

    // ---- CSR build (once, reused by all 3 layers) ----
    hipMemsetAsync(ptr, 0, (size_t)(N + 1) * sizeof(int), stream);
    hist_kernel<<<cdiv(E, 256), 256, 0, stream>>>(ei, E, ptr);
    scan_kernel<<<1, 256, 0, stream>>>(ptr, N + 1);
    scatter_kernel<<<cdiv(E, 256), 256, 0, stream>>>(ei, E, ptr, col);

    // ================= layer 1: 128 -> 8 heads x 16 =================
    gemm_kernel<128, 128><<<cdiv((long)N * 128, 256), 256, 0, stream>>>(x, W1, h, N);
    alpha_kernel<8, 16><<<cdiv((long)N * 8, 256), 256, 0, stream>>>(h, as1, ad1, asrc, adst, N);
    agg_csr_kernel<8, 16><<<N, 128, 0, stream>>>(ptr, col, asrc, adst, h, agg, N);
    ln_elu_kernel<128><<<cdiv(N, 4), 256, 0, stream>>>(agg, b1, g1, be1, N);

    // ================= layer 2: 128 -> 4 heads x 16 =================
    gemm_kernel<128, 64><<<cdiv((long)N * 64, 256), 256, 0, stream>>>(agg, W2, h, N);
    alpha_kernel<4, 16><<<cdiv((long)N * 4, 256), 256, 0, stream>>>(h, as2, ad2, asrc, adst, N);
    agg_csr_kernel<4, 16><<<N, 64, 0, stream>>>(ptr, col, asrc, adst, h, agg, N);
    ln_elu_kernel<64><<<cdiv(N, 4), 256, 0, stream>>>(agg, b2, g2, be2, N);

    // ================= layer 3: 64 -> 1 head x 10, mean(=identity) ==
    gemm_kernel<64, 10><<<cdiv((long)N * 10, 256), 256, 0, stream>>>(agg, W3, h, N);
    alpha_kernel<1, 10><<<cdiv(N, 256), 256, 0, stream>>>(h, as3, ad3, asrc, adst, N);
    agg_csr_l3<<<cdiv(N, 4), 256, 0, stream>>>(ptr, col, asrc, adst, h, agg, N);
    final_kernel<<<cdiv(N, 256), 256, 0, stream>>>(agg, b3, (float*)d_out, N);
}

// Round 4
// 1418.505 us; speedup vs baseline: 14.8456x; 1.2854x over previous
//
#include <hip/hip_runtime.h>
#include <hip/hip_bf16.h>
#include <math.h>

// ---------------- GEMM: Hout[n][m] = sum_k X[n][k] * W[k][m] ----------------
template<int K, int M>
__global__ __launch_bounds__(256) void gemm_kernel(
    const float* __restrict__ X, const float* __restrict__ W,
    float* __restrict__ Hout, int N)
{
    int gid = blockIdx.x * 256 + threadIdx.x;
    if (gid >= N * M) return;
    int n = gid / M;
    int m = gid - n * M;
    const float* xr = X + (size_t)n * K;
    float acc = 0.f;
    #pragma unroll 8
    for (int k = 0; k < K; ++k)
        acc += xr[k] * W[k * M + m];
    Hout[gid] = acc;
}

// ---------------- alpha_src/alpha_dst: [N,H] = sum_f h[n,hd,f]*a[hd,f] ------
template<int H, int F>
__global__ __launch_bounds__(256) void alpha_kernel(
    const float* __restrict__ h, const float* __restrict__ av_src,
    const float* __restrict__ av_dst, float* __restrict__ asrc,
    float* __restrict__ adst, int N)
{
    int gid = blockIdx.x * 256 + threadIdx.x;
    if (gid >= N * H) return;
    int n = gid / H;
    int hd = gid - n * H;
    const float* hr = h + (size_t)n * (H * F) + hd * F;
    float s1 = 0.f, s2 = 0.f;
    #pragma unroll
    for (int f = 0; f < F; ++f) {
        float v = hr[f];
        s1 += v * av_src[hd * F + f];
        s2 += v * av_dst[hd * F + f];
    }
    asrc[gid] = s1;
    adst[gid] = s2;
}

// ---------------- CSR build: histogram -> 2-level scan -> scatter -----------
__global__ __launch_bounds__(256) void hist_kernel(
    const int* __restrict__ ei, int E, int* __restrict__ ptr)
{
    int i = blockIdx.x * 256 + threadIdx.x;
    if (i >= E) return;
    atomicAdd(&ptr[ei[E + i] + 1], 1);
}

// level A: each block scans a 256-elem chunk in place, emits chunk total
__global__ __launch_bounds__(256) void scan_chunk_kernel(
    int* __restrict__ p, int n, int* __restrict__ sums)
{
    __shared__ int sm[256];
    int tid = threadIdx.x;
    int i = blockIdx.x * 256 + tid;
    sm[tid] = (i < n) ? p[i] : 0;
    __syncthreads();
    #pragma unroll
    for (int o = 1; o < 256; o <<= 1) {
        int t = (tid >= o) ? sm[tid - o] : 0;
        __syncthreads();
        sm[tid] += t;
        __syncthreads();
    }
    if (i < n) p[i] = sm[tid];
    if (tid == 255) sums[blockIdx.x] = sm[255];
}

// level B: single block scans the chunk totals (nc <= a few thousand)
__global__ __launch_bounds__(256) void scan_sums_kernel(int* __restrict__ s, int nc)
{
    __shared__ int sm[256];
    int tid = threadIdx.x;
    int carry = 0;
    for (int base = 0; base < nc; base += 256) {
        int i = base + tid;
        sm[tid] = (i < nc) ? s[i] : 0;
        __syncthreads();
        #pragma unroll
        for (int o = 1; o < 256; o <<= 1) {
            int t = (tid >= o) ? sm[tid - o] : 0;
            __syncthreads();
            sm[tid] += t;
            __syncthreads();
        }
        if (i < nc) s[i] = sm[tid] + carry;
        carry += sm[255];
        __syncthreads();
    }
}

// level C: add exclusive chunk offset
__global__ __launch_bounds__(256) void scan_add_kernel(
    int* __restrict__ p, int n, const int* __restrict__ sums)
{
    int c = blockIdx.x;
    if (c == 0) return;
    int i = c * 256 + threadIdx.x;
    if (i < n) p[i] += sums[c - 1];
}

// after scatter, ptr[d] becomes END of node d; start = (d?ptr[d-1]:0)
__global__ __launch_bounds__(256) void scatter_kernel(
    const int* __restrict__ ei, int E, int* __restrict__ ptr,
    int* __restrict__ col)
{
    int i = blockIdx.x * 256 + threadIdx.x;
    if (i >= E) return;
    int src = ei[i];
    int dst = ei[E + i];
    int pos = atomicAdd(&ptr[dst], 1);
    col[pos] = src;
}

// ---------------- CSR aggregation: one block (H*F threads) per dst ----------
template<int H, int F>
__global__ __launch_bounds__(H * F) void agg_csr_kernel(
    const int* __restrict__ ptr, const int* __restrict__ col,
    const float* __restrict__ asrc, const float* __restrict__ adst,
    const float* __restrict__ h, float* __restrict__ out, int N)
{
    int d = blockIdx.x;
    int tid = threadIdx.x;
    int hd = tid / F;
    int start = (d == 0) ? 0 : ptr[d - 1];
    int end = ptr[d];
    float adst_h = adst[d * H + hd];
    float lg = asrc[d * H + hd] + adst_h;
    lg = lg > 0.f ? lg : 0.2f * lg;
    float w = __expf(lg);
    float acc = w * h[(size_t)d * (H * F) + tid];
    float den = w;
    for (int e = start; e < end; ++e) {
        int s = col[e];
        float lg2 = asrc[s * H + hd] + adst_h;
        lg2 = lg2 > 0.f ? lg2 : 0.2f * lg2;
        float w2 = __expf(lg2);
        acc += w2 * h[(size_t)s * (H * F) + tid];
        den += w2;
    }
    out[(size_t)d * (H * F) + tid] = acc / (den + 1e-16f);
}

// ---------------- layer-3 aggregation: one wave per dst, H=1, F=10 ----------
__global__ __launch_bounds__(256) void agg_csr_l3(
    const int* __restrict__ ptr, const int* __restrict__ col,
    const float* __restrict__ asrc, const float* __restrict__ adst,
    const float* __restrict__ h, float* __restrict__ out, int N)
{
    int wave = threadIdx.x >> 6;
    int lane = threadIdx.x & 63;
    int d = blockIdx.x * 4 + wave;
    if (d >= N) return;
    int start = (d == 0) ? 0 : ptr[d - 1];
    int end = ptr[d];
    float adst_d = adst[d];
    float lg = asrc[d] + adst_d;
    lg = lg > 0.f ? lg : 0.2f * lg;
    float w = __expf(lg);
    float acc = (lane < 10) ? w * h[(size_t)d * 10 + lane] : 0.f;
    float den = w;
    for (int e = start; e < end; ++e) {
        int s = col[e];
        float lg2 = asrc[s] + adst_d;
        lg2 = lg2 > 0.f ? lg2 : 0.2f * lg2;
        float w2 = __expf(lg2);
        if (lane < 10) acc += w2 * h[(size_t)s * 10 + lane];
        den += w2;
    }
    if (lane < 10) out[(size_t)d * 10 + lane] = acc / (den + 1e-16f);
}

// ---------------- bias + LayerNorm + ELU (one wave per node) ----------------
template<int M>
__global__ __launch_bounds__(256) void ln_elu_kernel(
    float* __restrict__ x, const float* __restrict__ bias,
    const float* __restrict__ g, const float* __restrict__ be, int N)
{
    int n = blockIdx.x * 4 + (threadIdx.x >> 6);
    int lane = threadIdx.x & 63;
    if (n >= N) return;
    float* row = x + (size_t)n * M;
    constexpr int PER = M / 64;
    float v[PER];
    float sum = 0.f;
    #pragma unroll
    for (int p = 0; p < PER; ++p) {
        int m = lane + p * 64;
        v[p] = row[m] + bias[m];
        sum += v[p];
    }
    #pragma unroll
    for (int o = 32; o >= 1; o >>= 1) sum += __shfl_xor(sum, o, 64);
    float mu = sum * (1.0f / M);
    float vs = 0.f;
    #pragma unroll
    for (int p = 0; p < PER; ++p) { float d = v[p] - mu; vs += d * d; }
    #pragma unroll
    for (int o = 32; o >= 1; o >>= 1) vs += __shfl_xor(vs, o, 64);
    float inv = rsqrtf(vs * (1.0f / M) + 1e-5f);
    #pragma unroll
    for (int p = 0; p < PER; ++p) {
        int m = lane + p * 64;
        float y = (v[p] - mu) * inv * g[m] + be[m];
        y = y > 0.f ? y : expm1f(y);
        row[m] = y;
    }
}

// ---------------- final: +bias then log_softmax over 10, write fp32 ---------
__global__ __launch_bounds__(256) void final_kernel(
    const float* __restrict__ agg, const float* __restrict__ b3,
    float* __restrict__ out, int N)
{
    int n = blockIdx.x * 256 + threadIdx.x;
    if (n >= N) return;
    float v[10];
    float mx = -1e30f;
    #pragma unroll
    for (int j = 0; j < 10; ++j) {
        v[j] = agg[(size_t)n * 10 + j] + b3[j];
        mx = fmaxf(mx, v[j]);
    }
    float se = 0.f;
    #pragma unroll
    for (int j = 0; j < 10; ++j) se += __expf(v[j] - mx);
    float ls = mx + logf(se);
    #pragma unroll
    for (int j = 0; j < 10; ++j)
        out[(size_t)n * 10 + j] = v[j] - ls;
}

static inline int cdiv(long a, long b) { return (int)((a + b - 1) / b); }

extern "C" void kernel_launch(void* const* d_in, const int* in_sizes, int n_in,
                              void* d_out, int out_size, void* d_ws, size_t ws_size,
                              hipStream_t stream)
{
    const float* x   = (const float*)d_in[0];
    const int*   ei  = (const int*)d_in[1];
    const float* W1  = (const float*)d_in[2];
    const float* as1 = (const float*)d_in[3];
    const float* ad1 = (const float*)d_in[4];
    const float* b1  = (const float*)d_in[5];
    const float* g1  = (const float*)d_in[6];
    const float* be1 = (const float*)d_in[7];
    const float* W2  = (const float*)d_in[8];
    const float* as2 = (const float*)d_in[9];
    const float* ad2 = (const float*)d_in[10];
    const float* b2  = (const float*)d_in[11];
    const float* g2  = (const float*)d_in[12];
    const float* be2 = (const float*)d_in[13];
    const float* W3  = (const float*)d_in[14];
    const float* as3 = (const float*)d_in[15];
    const float* ad3 = (const float*)d_in[16];
    const float* b3  = (const float*)d_in[17];

    const int N = in_sizes[0] / 128;
    const int E = in_sizes[1] / 2;

    float* h    = (float*)d_ws;              // N*128
    float* agg  = h + (size_t)N * 128;       // N*128
    float* asrc = agg + (size_t)N * 128;     // N*8
    float* adst = asrc + (size_t)N * 8;      // N*8
    int*   ptr  = (int*)(adst + (size_t)N * 8); // N+1
    int*   col  = ptr + (N + 1);             // E
    int*   sums = col + E;                   // cdiv(N+1,256)

    const int nScan = N + 1;
    const int nChunks = cdiv(nScan, 256);

    // ---- CSR build (once, reused by all 3 layers) ----
    hipMemsetAsync(ptr, 0, (size_t)nScan * sizeof(int), stream);
    hist_kernel<<<cdiv(E, 256), 256, 0, stream>>>(ei, E, ptr);
    scan_chunk_kernel<<<nChunks, 256, 0, stream>>>(ptr, nScan, sums);
    scan_sums_kernel<<<1, 256, 0, stream>>>(sums, nChunks);
    scan_add_kernel<<<nChunks, 256, 0, stream>>>(ptr, nScan, sums);
    scatter_kernel<<<cdiv(E, 256), 256, 0, stream>>>(ei, E, ptr, col);

    // ================= layer 1: 128 -> 8 heads x 16 =================
    gemm_kernel<128, 128><<<cdiv((long)N * 128, 256), 256, 0, stream>>>(x, W1, h, N);
    alpha_kernel<8, 16><<<cdiv((long)N * 8, 256), 256, 0, stream>>>(h, as1, ad1, asrc, adst, N);
    agg_csr_kernel<8, 16><<<N, 128, 0, stream>>>(ptr, col, asrc, adst, h, agg, N);
    ln_elu_kernel<128><<<cdiv(N, 4), 256, 0, stream>>>(agg, b1, g1, be1, N);

    // ================= layer 2: 128 -> 4 heads x 16 =================
    gemm_kernel<128, 64><<<cdiv((long)N * 64, 256), 256, 0, stream>>>(agg, W2, h, N);
    alpha_kernel<4, 16><<<cdiv((long)N * 4, 256), 256, 0, stream>>>(h, as2, ad2, asrc, adst, N);
    agg_csr_kernel<4, 16><<<N, 64, 0, stream>>>(ptr, col, asrc, adst, h, agg, N);
    ln_elu_kernel<64><<<cdiv(N, 4), 256, 0, stream>>>(agg, b2, g2, be2, N);

    // ================= layer 3: 64 -> 1 head x 10, mean(=identity) ==
    gemm_kernel<64, 10><<<cdiv((long)N * 10, 256), 256, 0, stream>>>(agg, W3, h, N);
    alpha_kernel<1, 10><<<cdiv(N, 256), 256, 0, stream>>>(h, as3, ad3, asrc, adst, N);
    agg_csr_l3<<<cdiv(N, 4), 256, 0, stream>>>(ptr, col, asrc, adst, h, agg, N);
    final_kernel<<<cdiv(N, 256), 256, 0, stream>>>(agg, b3, (float*)d_out, N);
}

// Round 5
// 967.895 us; speedup vs baseline: 21.7571x; 1.4656x over previous
//
#include <hip/hip_runtime.h>
#include <hip/hip_bf16.h>
#include <math.h>

// ---------------- naive GEMM (kept for tiny layer 3) ------------------------
template<int K, int M>
__global__ __launch_bounds__(256) void gemm_kernel(
    const float* __restrict__ X, const float* __restrict__ W,
    float* __restrict__ Hout, int N)
{
    int gid = blockIdx.x * 256 + threadIdx.x;
    if (gid >= N * M) return;
    int n = gid / M;
    int m = gid - n * M;
    const float* xr = X + (size_t)n * K;
    float acc = 0.f;
    #pragma unroll 8
    for (int k = 0; k < K; ++k)
        acc += xr[k] * W[k * M + m];
    Hout[gid] = acc;
}

// ---------------- LDS-tiled register-blocked GEMM ---------------------------
// C[N,M] = X[N,K] @ W[K,M].  256 threads; thread micro-tile TM x TN (TN==4).
// Xs padded stride BK+4 -> inner X reads 2-addr/wave (free); 16B-aligned rows.
template<int K, int M, int BM, int BK, int TM, int TN>
__global__ __launch_bounds__(256) void gemm_tiled(
    const float* __restrict__ X, const float* __restrict__ W,
    float* __restrict__ Hout, int N)
{
    constexpr int BKP = BK + 4;
    __shared__ float Xs[BM * BKP];
    __shared__ float Ws[BK * M];
    constexpr int NCG = M / TN;      // col groups
    constexpr int NRG = 256 / NCG;   // row groups
    static_assert(NRG * TM == BM, "tile mismatch");
    static_assert(TN == 4, "TN must be 4");
    int tid = threadIdx.x;
    int mcol = (tid % NCG) * TN;
    int mrow = (tid / NCG) * TM;
    int r0 = blockIdx.x * BM;

    float acc[TM][TN];
    #pragma unroll
    for (int i = 0; i < TM; ++i)
        #pragma unroll
        for (int j = 0; j < TN; ++j) acc[i][j] = 0.f;

    for (int k0 = 0; k0 < K; k0 += BK) {
        constexpr int XF4 = BM * BK / 4;
        for (int f = tid; f < XF4; f += 256) {
            int n = f / (BK / 4);
            int kq = f % (BK / 4);
            int row = r0 + n;
            float4 v = make_float4(0.f, 0.f, 0.f, 0.f);
            if (row < N)
                v = *reinterpret_cast<const float4*>(X + (size_t)row * K + k0 + kq * 4);
            *reinterpret_cast<float4*>(&Xs[n * BKP + kq * 4]) = v;
        }
        constexpr int WF4 = BK * M / 4;
        for (int f = tid; f < WF4; f += 256) {
            int kr = f / (M / 4);
            int mq = f % (M / 4);
            *reinterpret_cast<float4*>(&Ws[kr * M + mq * 4]) =
                *reinterpret_cast<const float4*>(W + (size_t)(k0 + kr) * M + mq * 4);
        }
        __syncthreads();
        #pragma unroll
        for (int k = 0; k < BK; ++k) {
            float xv[TM];
            #pragma unroll
            for (int i = 0; i < TM; ++i) xv[i] = Xs[(mrow + i) * BKP + k];
            float4 wv = *reinterpret_cast<const float4*>(&Ws[k * M + mcol]);
            #pragma unroll
            for (int i = 0; i < TM; ++i) {
                acc[i][0] += xv[i] * wv.x;
                acc[i][1] += xv[i] * wv.y;
                acc[i][2] += xv[i] * wv.z;
                acc[i][3] += xv[i] * wv.w;
            }
        }
        __syncthreads();
    }
    #pragma unroll
    for (int i = 0; i < TM; ++i) {
        int row = r0 + mrow + i;
        if (row < N)
            *reinterpret_cast<float4*>(Hout + (size_t)row * M + mcol) =
                make_float4(acc[i][0], acc[i][1], acc[i][2], acc[i][3]);
    }
}

// ---------------- alpha_src/alpha_dst: [N,H] = sum_f h[n,hd,f]*a[hd,f] ------
template<int H, int F>
__global__ __launch_bounds__(256) void alpha_kernel(
    const float* __restrict__ h, const float* __restrict__ av_src,
    const float* __restrict__ av_dst, float* __restrict__ asrc,
    float* __restrict__ adst, int N)
{
    int gid = blockIdx.x * 256 + threadIdx.x;
    if (gid >= N * H) return;
    int n = gid / H;
    int hd = gid - n * H;
    const float* hr = h + (size_t)n * (H * F) + hd * F;
    float s1 = 0.f, s2 = 0.f;
    #pragma unroll
    for (int f = 0; f < F; ++f) {
        float v = hr[f];
        s1 += v * av_src[hd * F + f];
        s2 += v * av_dst[hd * F + f];
    }
    asrc[gid] = s1;
    adst[gid] = s2;
}

// ---------------- CSR build: histogram -> 2-level scan -> scatter -----------
__global__ __launch_bounds__(256) void hist_kernel(
    const int* __restrict__ ei, int E, int* __restrict__ ptr)
{
    int i = blockIdx.x * 256 + threadIdx.x;
    if (i >= E) return;
    atomicAdd(&ptr[ei[E + i] + 1], 1);
}

__global__ __launch_bounds__(256) void scan_chunk_kernel(
    int* __restrict__ p, int n, int* __restrict__ sums)
{
    __shared__ int sm[256];
    int tid = threadIdx.x;
    int i = blockIdx.x * 256 + tid;
    sm[tid] = (i < n) ? p[i] : 0;
    __syncthreads();
    #pragma unroll
    for (int o = 1; o < 256; o <<= 1) {
        int t = (tid >= o) ? sm[tid - o] : 0;
        __syncthreads();
        sm[tid] += t;
        __syncthreads();
    }
    if (i < n) p[i] = sm[tid];
    if (tid == 255) sums[blockIdx.x] = sm[255];
}

__global__ __launch_bounds__(256) void scan_sums_kernel(int* __restrict__ s, int nc)
{
    __shared__ int sm[256];
    int tid = threadIdx.x;
    int carry = 0;
    for (int base = 0; base < nc; base += 256) {
        int i = base + tid;
        sm[tid] = (i < nc) ? s[i] : 0;
        __syncthreads();
        #pragma unroll
        for (int o = 1; o < 256; o <<= 1) {
            int t = (tid >= o) ? sm[tid - o] : 0;
            __syncthreads();
            sm[tid] += t;
            __syncthreads();
        }
        if (i < nc) s[i] = sm[tid] + carry;
        carry += sm[255];
        __syncthreads();
    }
}

__global__ __launch_bounds__(256) void scan_add_kernel(
    int* __restrict__ p, int n, const int* __restrict__ sums)
{
    int c = blockIdx.x;
    if (c == 0) return;
    int i = c * 256 + threadIdx.x;
    if (i < n) p[i] += sums[c - 1];
}

// after scatter, ptr[d] becomes END of node d; start = (d?ptr[d-1]:0)
__global__ __launch_bounds__(256) void scatter_kernel(
    const int* __restrict__ ei, int E, int* __restrict__ ptr,
    int* __restrict__ col)
{
    int i = blockIdx.x * 256 + threadIdx.x;
    if (i >= E) return;
    int src = ei[i];
    int dst = ei[E + i];
    int pos = atomicAdd(&ptr[dst], 1);
    col[pos] = src;
}

// ---------------- CSR aggregation: one block (H*F threads) per dst ----------
template<int H, int F>
__global__ __launch_bounds__(H * F) void agg_csr_kernel(
    const int* __restrict__ ptr, const int* __restrict__ col,
    const float* __restrict__ asrc, const float* __restrict__ adst,
    const float* __restrict__ h, float* __restrict__ out, int N)
{
    int d = blockIdx.x;
    int tid = threadIdx.x;
    int hd = tid / F;
    int start = (d == 0) ? 0 : ptr[d - 1];
    int end = ptr[d];
    float adst_h = adst[d * H + hd];
    float lg = asrc[d * H + hd] + adst_h;
    lg = lg > 0.f ? lg : 0.2f * lg;
    float w = __expf(lg);
    float acc = w * h[(size_t)d * (H * F) + tid];
    float den = w;
    for (int e = start; e < end; ++e) {
        int s = col[e];
        float lg2 = asrc[s * H + hd] + adst_h;
        lg2 = lg2 > 0.f ? lg2 : 0.2f * lg2;
        float w2 = __expf(lg2);
        acc += w2 * h[(size_t)s * (H * F) + tid];
        den += w2;
    }
    out[(size_t)d * (H * F) + tid] = acc / (den + 1e-16f);
}

// ---------------- layer-3 aggregation: one wave per dst, H=1, F=10 ----------
__global__ __launch_bounds__(256) void agg_csr_l3(
    const int* __restrict__ ptr, const int* __restrict__ col,
    const float* __restrict__ asrc, const float* __restrict__ adst,
    const float* __restrict__ h, float* __restrict__ out, int N)
{
    int wave = threadIdx.x >> 6;
    int lane = threadIdx.x & 63;
    int d = blockIdx.x * 4 + wave;
    if (d >= N) return;
    int start = (d == 0) ? 0 : ptr[d - 1];
    int end = ptr[d];
    float adst_d = adst[d];
    float lg = asrc[d] + adst_d;
    lg = lg > 0.f ? lg : 0.2f * lg;
    float w = __expf(lg);
    float acc = (lane < 10) ? w * h[(size_t)d * 10 + lane] : 0.f;
    float den = w;
    for (int e = start; e < end; ++e) {
        int s = col[e];
        float lg2 = asrc[s] + adst_d;
        lg2 = lg2 > 0.f ? lg2 : 0.2f * lg2;
        float w2 = __expf(lg2);
        if (lane < 10) acc += w2 * h[(size_t)s * 10 + lane];
        den += w2;
    }
    if (lane < 10) out[(size_t)d * 10 + lane] = acc / (den + 1e-16f);
}

// ---------------- bias + LayerNorm + ELU (one wave per node) ----------------
template<int M>
__global__ __launch_bounds__(256) void ln_elu_kernel(
    float* __restrict__ x, const float* __restrict__ bias,
    const float* __restrict__ g, const float* __restrict__ be, int N)
{
    int n = blockIdx.x * 4 + (threadIdx.x >> 6);
    int lane = threadIdx.x & 63;
    if (n >= N) return;
    float* row = x + (size_t)n * M;
    constexpr int PER = M / 64;
    float v[PER];
    float sum = 0.f;
    #pragma unroll
    for (int p = 0; p < PER; ++p) {
        int m = lane + p * 64;
        v[p] = row[m] + bias[m];
        sum += v[p];
    }
    #pragma unroll
    for (int o = 32; o >= 1; o >>= 1) sum += __shfl_xor(sum, o, 64);
    float mu = sum * (1.0f / M);
    float vs = 0.f;
    #pragma unroll
    for (int p = 0; p < PER; ++p) { float d = v[p] - mu; vs += d * d; }
    #pragma unroll
    for (int o = 32; o >= 1; o >>= 1) vs += __shfl_xor(vs, o, 64);
    float inv = rsqrtf(vs * (1.0f / M) + 1e-5f);
    #pragma unroll
    for (int p = 0; p < PER; ++p) {
        int m = lane + p * 64;
        float y = (v[p] - mu) * inv * g[m] + be[m];
        y = y > 0.f ? y : expm1f(y);
        row[m] = y;
    }
}

// ---------------- final: +bias then log_softmax over 10, write fp32 ---------
__global__ __launch_bounds__(256) void final_kernel(
    const float* __restrict__ agg, const float* __restrict__ b3,
    float* __restrict__ out, int N)
{
    int n = blockIdx.x * 256 + threadIdx.x;
    if (n >= N) return;
    float v[10];
    float mx = -1e30f;
    #pragma unroll
    for (int j = 0; j < 10; ++j) {
        v[j] = agg[(size_t)n * 10 + j] + b3[j];
        mx = fmaxf(mx, v[j]);
    }
    float se = 0.f;
    #pragma unroll
    for (int j = 0; j < 10; ++j) se += __expf(v[j] - mx);
    float ls = mx + logf(se);
    #pragma unroll
    for (int j = 0; j < 10; ++j)
        out[(size_t)n * 10 + j] = v[j] - ls;
}

static inline int cdiv(long a, long b) { return (int)((a + b - 1) / b); }

extern "C" void kernel_launch(void* const* d_in, const int* in_sizes, int n_in,
                              void* d_out, int out_size, void* d_ws, size_t ws_size,
                              hipStream_t stream)
{
    const float* x   = (const float*)d_in[0];
    const int*   ei  = (const int*)d_in[1];
    const float* W1  = (const float*)d_in[2];
    const float* as1 = (const float*)d_in[3];
    const float* ad1 = (const float*)d_in[4];
    const float* b1  = (const float*)d_in[5];
    const float* g1  = (const float*)d_in[6];
    const float* be1 = (const float*)d_in[7];
    const float* W2  = (const float*)d_in[8];
    const float* as2 = (const float*)d_in[9];
    const float* ad2 = (const float*)d_in[10];
    const float* b2  = (const float*)d_in[11];
    const float* g2  = (const float*)d_in[12];
    const float* be2 = (const float*)d_in[13];
    const float* W3  = (const float*)d_in[14];
    const float* as3 = (const float*)d_in[15];
    const float* ad3 = (const float*)d_in[16];
    const float* b3  = (const float*)d_in[17];

    const int N = in_sizes[0] / 128;
    const int E = in_sizes[1] / 2;

    float* h    = (float*)d_ws;              // N*128
    float* agg  = h + (size_t)N * 128;       // N*128
    float* asrc = agg + (size_t)N * 128;     // N*8
    float* adst = asrc + (size_t)N * 8;      // N*8
    int*   ptr  = (int*)(adst + (size_t)N * 8); // N+1
    int*   col  = ptr + (N + 1);             // E
    int*   sums = col + E;                   // cdiv(N+1,256)

    const int nScan = N + 1;
    const int nChunks = cdiv(nScan, 256);

    // ---- CSR build (once, reused by all 3 layers) ----
    hipMemsetAsync(ptr, 0, (size_t)nScan * sizeof(int), stream);
    hist_kernel<<<cdiv(E, 256), 256, 0, stream>>>(ei, E, ptr);
    scan_chunk_kernel<<<nChunks, 256, 0, stream>>>(ptr, nScan, sums);
    scan_sums_kernel<<<1, 256, 0, stream>>>(sums, nChunks);
    scan_add_kernel<<<nChunks, 256, 0, stream>>>(ptr, nScan, sums);
    scatter_kernel<<<cdiv(E, 256), 256, 0, stream>>>(ei, E, ptr, col);

    // ================= layer 1: 128 -> 8 heads x 16 =================
    gemm_tiled<128, 128, 64, 64, 8, 4><<<cdiv(N, 64), 256, 0, stream>>>(x, W1, h, N);
    alpha_kernel<8, 16><<<cdiv((long)N * 8, 256), 256, 0, stream>>>(h, as1, ad1, asrc, adst, N);
    agg_csr_kernel<8, 16><<<N, 128, 0, stream>>>(ptr, col, asrc, adst, h, agg, N);
    ln_elu_kernel<128><<<cdiv(N, 4), 256, 0, stream>>>(agg, b1, g1, be1, N);

    // ================= layer 2: 128 -> 4 heads x 16 =================
    gemm_tiled<128, 64, 128, 64, 8, 4><<<cdiv(N, 128), 256, 0, stream>>>(agg, W2, h, N);
    alpha_kernel<4, 16><<<cdiv((long)N * 4, 256), 256, 0, stream>>>(h, as2, ad2, asrc, adst, N);
    agg_csr_kernel<4, 16><<<N, 64, 0, stream>>>(ptr, col, asrc, adst, h, agg, N);
    ln_elu_kernel<64><<<cdiv(N, 4), 256, 0, stream>>>(agg, b2, g2, be2, N);

    // ================= layer 3: 64 -> 1 head x 10, mean(=identity) ==
    gemm_kernel<64, 10><<<cdiv((long)N * 10, 256), 256, 0, stream>>>(agg, W3, h, N);
    alpha_kernel<1, 10><<<cdiv(N, 256), 256, 0, stream>>>(h, as3, ad3, asrc, adst, N);
    agg_csr_l3<<<cdiv(N, 4), 256, 0, stream>>>(ptr, col, asrc, adst, h, agg, N);
    final_kernel<<<cdiv(N, 256), 256, 0, stream>>>(agg, b3, (float*)d_out, N);
}

// Round 6
// 926.412 us; speedup vs baseline: 22.7313x; 1.0448x over previous
//
#include <hip/hip_runtime.h>
#include <hip/hip_bf16.h>
#include <math.h>

typedef __hip_bfloat16 bf16;

__device__ __forceinline__ float ldf(const float* p, size_t i) { return p[i]; }
__device__ __forceinline__ float ldf(const bf16* p, size_t i) { return __bfloat162float(p[i]); }

// ---------------- naive GEMM (kept for tiny layer 3) ------------------------
template<int K, int M>
__global__ __launch_bounds__(256) void gemm_kernel(
    const float* __restrict__ X, const float* __restrict__ W,
    float* __restrict__ Hout, int N)
{
    int gid = blockIdx.x * 256 + threadIdx.x;
    if (gid >= N * M) return;
    int n = gid / M;
    int m = gid - n * M;
    const float* xr = X + (size_t)n * K;
    float acc = 0.f;
    #pragma unroll 8
    for (int k = 0; k < K; ++k)
        acc += xr[k] * W[k * M + m];
    Hout[gid] = acc;
}

// ---------------- LDS-tiled register-blocked GEMM, bf16 output --------------
// C[N,M] = X[N,K] @ W[K,M].  256 threads; thread micro-tile TM x 4.
template<int K, int M, int BM, int BK, int TM>
__global__ __launch_bounds__(256) void gemm_tiled_bf(
    const float* __restrict__ X, const float* __restrict__ W,
    bf16* __restrict__ Hout, int N)
{
    constexpr int BKP = BK + 4;
    __shared__ float Xs[BM * BKP];
    __shared__ float Ws[BK * M];
    constexpr int NCG = M / 4;       // col groups
    constexpr int NRG = 256 / NCG;   // row groups
    static_assert(NRG * TM == BM, "tile mismatch");
    int tid = threadIdx.x;
    int mcol = (tid % NCG) * 4;
    int mrow = (tid / NCG) * TM;
    int r0 = blockIdx.x * BM;

    float acc[TM][4];
    #pragma unroll
    for (int i = 0; i < TM; ++i)
        #pragma unroll
        for (int j = 0; j < 4; ++j) acc[i][j] = 0.f;

    for (int k0 = 0; k0 < K; k0 += BK) {
        constexpr int XF4 = BM * BK / 4;
        for (int f = tid; f < XF4; f += 256) {
            int n = f / (BK / 4);
            int kq = f % (BK / 4);
            int row = r0 + n;
            float4 v = make_float4(0.f, 0.f, 0.f, 0.f);
            if (row < N)
                v = *reinterpret_cast<const float4*>(X + (size_t)row * K + k0 + kq * 4);
            *reinterpret_cast<float4*>(&Xs[n * BKP + kq * 4]) = v;
        }
        constexpr int WF4 = BK * M / 4;
        for (int f = tid; f < WF4; f += 256) {
            int kr = f / (M / 4);
            int mq = f % (M / 4);
            *reinterpret_cast<float4*>(&Ws[kr * M + mq * 4]) =
                *reinterpret_cast<const float4*>(W + (size_t)(k0 + kr) * M + mq * 4);
        }
        __syncthreads();
        #pragma unroll
        for (int k = 0; k < BK; ++k) {
            float xv[TM];
            #pragma unroll
            for (int i = 0; i < TM; ++i) xv[i] = Xs[(mrow + i) * BKP + k];
            float4 wv = *reinterpret_cast<const float4*>(&Ws[k * M + mcol]);
            #pragma unroll
            for (int i = 0; i < TM; ++i) {
                acc[i][0] += xv[i] * wv.x;
                acc[i][1] += xv[i] * wv.y;
                acc[i][2] += xv[i] * wv.z;
                acc[i][3] += xv[i] * wv.w;
            }
        }
        __syncthreads();
    }
    #pragma unroll
    for (int i = 0; i < TM; ++i) {
        int row = r0 + mrow + i;
        if (row < N) {
            alignas(8) bf16 pk[4];
            #pragma unroll
            for (int j = 0; j < 4; ++j) pk[j] = __float2bfloat16(acc[i][j]);
            *reinterpret_cast<uint2*>(Hout + (size_t)row * M + mcol) =
                *reinterpret_cast<uint2*>(pk);
        }
    }
}

// ---------------- alpha_src/alpha_dst: [N,H] = sum_f h[n,hd,f]*a[hd,f] ------
template<typename T, int H, int F>
__global__ __launch_bounds__(256) void alpha_kernel(
    const T* __restrict__ h, const float* __restrict__ av_src,
    const float* __restrict__ av_dst, float* __restrict__ asrc,
    float* __restrict__ adst, int N)
{
    int gid = blockIdx.x * 256 + threadIdx.x;
    if (gid >= N * H) return;
    int n = gid / H;
    int hd = gid - n * H;
    const T* hr = h + (size_t)n * (H * F) + hd * F;
    float s1 = 0.f, s2 = 0.f;
    #pragma unroll
    for (int f = 0; f < F; ++f) {
        float v = ldf(hr, f);
        s1 += v * av_src[hd * F + f];
        s2 += v * av_dst[hd * F + f];
    }
    asrc[gid] = s1;
    adst[gid] = s2;
}

// ---------------- CSR build: histogram -> 2-level scan -> scatter -----------
__global__ __launch_bounds__(256) void hist_kernel(
    const int* __restrict__ ei, int E, int* __restrict__ ptr)
{
    int i = blockIdx.x * 256 + threadIdx.x;
    if (i >= E) return;
    atomicAdd(&ptr[ei[E + i] + 1], 1);
}

__global__ __launch_bounds__(256) void scan_chunk_kernel(
    int* __restrict__ p, int n, int* __restrict__ sums)
{
    __shared__ int sm[256];
    int tid = threadIdx.x;
    int i = blockIdx.x * 256 + tid;
    sm[tid] = (i < n) ? p[i] : 0;
    __syncthreads();
    #pragma unroll
    for (int o = 1; o < 256; o <<= 1) {
        int t = (tid >= o) ? sm[tid - o] : 0;
        __syncthreads();
        sm[tid] += t;
        __syncthreads();
    }
    if (i < n) p[i] = sm[tid];
    if (tid == 255) sums[blockIdx.x] = sm[255];
}

__global__ __launch_bounds__(256) void scan_sums_kernel(int* __restrict__ s, int nc)
{
    __shared__ int sm[256];
    int tid = threadIdx.x;
    int carry = 0;
    for (int base = 0; base < nc; base += 256) {
        int i = base + tid;
        sm[tid] = (i < nc) ? s[i] : 0;
        __syncthreads();
        #pragma unroll
        for (int o = 1; o < 256; o <<= 1) {
            int t = (tid >= o) ? sm[tid - o] : 0;
            __syncthreads();
            sm[tid] += t;
            __syncthreads();
        }
        if (i < nc) s[i] = sm[tid] + carry;
        carry += sm[255];
        __syncthreads();
    }
}

__global__ __launch_bounds__(256) void scan_add_kernel(
    int* __restrict__ p, int n, const int* __restrict__ sums)
{
    int c = blockIdx.x;
    if (c == 0) return;
    int i = c * 256 + threadIdx.x;
    if (i < n) p[i] += sums[c - 1];
}

// after scatter, ptr[d] becomes END of node d; start = (d?ptr[d-1]:0)
__global__ __launch_bounds__(256) void scatter_kernel(
    const int* __restrict__ ei, int E, int* __restrict__ ptr,
    int* __restrict__ col)
{
    int i = blockIdx.x * 256 + threadIdx.x;
    if (i >= E) return;
    int src = ei[i];
    int dst = ei[E + i];
    int pos = atomicAdd(&ptr[dst], 1);
    col[pos] = src;
}

// ------- CSR aggregation + bias + LayerNorm + ELU fused (block = row) -------
template<int H, int F>
__global__ __launch_bounds__(H * F) void agg_ln_kernel(
    const int* __restrict__ ptr, const int* __restrict__ col,
    const float* __restrict__ asrc, const float* __restrict__ adst,
    const bf16* __restrict__ hb, const float* __restrict__ bias,
    const float* __restrict__ g, const float* __restrict__ be,
    float* __restrict__ out, int N)
{
    constexpr int M = H * F;
    int d = blockIdx.x;
    int tid = threadIdx.x;
    int hd = tid / F;
    int start = (d == 0) ? 0 : ptr[d - 1];
    int end = ptr[d];
    float adst_h = adst[d * H + hd];
    float lg = asrc[d * H + hd] + adst_h;
    lg = lg > 0.f ? lg : 0.2f * lg;
    float w = __expf(lg);
    float acc = w * __bfloat162float(hb[(size_t)d * M + tid]);
    float den = w;
    for (int e = start; e < end; ++e) {
        int s = col[e];
        float lg2 = asrc[s * H + hd] + adst_h;
        lg2 = lg2 > 0.f ? lg2 : 0.2f * lg2;
        float w2 = __expf(lg2);
        acc += w2 * __bfloat162float(hb[(size_t)s * M + tid]);
        den += w2;
    }
    float o = acc / (den + 1e-16f) + bias[tid];
    // block-wide LN over M values (one per thread)
    float s1 = o, s2 = o * o;
    #pragma unroll
    for (int off = 32; off >= 1; off >>= 1) {
        s1 += __shfl_xor(s1, off, 64);
        s2 += __shfl_xor(s2, off, 64);
    }
    if constexpr (M == 128) {
        __shared__ float red[4];
        int wv = tid >> 6;
        if ((tid & 63) == 0) { red[wv] = s1; red[2 + wv] = s2; }
        __syncthreads();
        s1 = red[0] + red[1];
        s2 = red[2] + red[3];
    }
    float mu = s1 * (1.f / M);
    float var = s2 * (1.f / M) - mu * mu;
    float inv = rsqrtf(var + 1e-5f);
    float y = (o - mu) * inv * g[tid] + be[tid];
    y = y > 0.f ? y : expm1f(y);
    out[(size_t)d * M + tid] = y;
}

// ---------------- layer-3 aggregation: one wave per dst, H=1, F=10 ----------
__global__ __launch_bounds__(256) void agg_csr_l3(
    const int* __restrict__ ptr, const int* __restrict__ col,
    const float* __restrict__ asrc, const float* __restrict__ adst,
    const float* __restrict__ h, float* __restrict__ out, int N)
{
    int wave = threadIdx.x >> 6;
    int lane = threadIdx.x & 63;
    int d = blockIdx.x * 4 + wave;
    if (d >= N) return;
    int start = (d == 0) ? 0 : ptr[d - 1];
    int end = ptr[d];
    float adst_d = adst[d];
    float lg = asrc[d] + adst_d;
    lg = lg > 0.f ? lg : 0.2f * lg;
    float w = __expf(lg);
    float acc = (lane < 10) ? w * h[(size_t)d * 10 + lane] : 0.f;
    float den = w;
    for (int e = start; e < end; ++e) {
        int s = col[e];
        float lg2 = asrc[s] + adst_d;
        lg2 = lg2 > 0.f ? lg2 : 0.2f * lg2;
        float w2 = __expf(lg2);
        if (lane < 10) acc += w2 * h[(size_t)s * 10 + lane];
        den += w2;
    }
    if (lane < 10) out[(size_t)d * 10 + lane] = acc / (den + 1e-16f);
}

// ---------------- final: +bias then log_softmax over 10, write fp32 ---------
__global__ __launch_bounds__(256) void final_kernel(
    const float* __restrict__ agg, const float* __restrict__ b3,
    float* __restrict__ out, int N)
{
    int n = blockIdx.x * 256 + threadIdx.x;
    if (n >= N) return;
    float v[10];
    float mx = -1e30f;
    #pragma unroll
    for (int j = 0; j < 10; ++j) {
        v[j] = agg[(size_t)n * 10 + j] + b3[j];
        mx = fmaxf(mx, v[j]);
    }
    float se = 0.f;
    #pragma unroll
    for (int j = 0; j < 10; ++j) se += __expf(v[j] - mx);
    float ls = mx + logf(se);
    #pragma unroll
    for (int j = 0; j < 10; ++j)
        out[(size_t)n * 10 + j] = v[j] - ls;
}

static inline int cdiv(long a, long b) { return (int)((a + b - 1) / b); }

extern "C" void kernel_launch(void* const* d_in, const int* in_sizes, int n_in,
                              void* d_out, int out_size, void* d_ws, size_t ws_size,
                              hipStream_t stream)
{
    const float* x   = (const float*)d_in[0];
    const int*   ei  = (const int*)d_in[1];
    const float* W1  = (const float*)d_in[2];
    const float* as1 = (const float*)d_in[3];
    const float* ad1 = (const float*)d_in[4];
    const float* b1  = (const float*)d_in[5];
    const float* g1  = (const float*)d_in[6];
    const float* be1 = (const float*)d_in[7];
    const float* W2  = (const float*)d_in[8];
    const float* as2 = (const float*)d_in[9];
    const float* ad2 = (const float*)d_in[10];
    const float* b2  = (const float*)d_in[11];
    const float* g2  = (const float*)d_in[12];
    const float* be2 = (const float*)d_in[13];
    const float* W3  = (const float*)d_in[14];
    const float* as3 = (const float*)d_in[15];
    const float* ad3 = (const float*)d_in[16];
    const float* b3  = (const float*)d_in[17];

    const int N = in_sizes[0] / 128;
    const int E = in_sizes[1] / 2;

    bf16*  hb   = (bf16*)d_ws;                      // N*128 bf16 (also fp32 N*10 for L3)
    float* agg  = (float*)(hb + (size_t)N * 128);   // N*128 fp32
    float* asrc = agg + (size_t)N * 128;            // N*8
    float* adst = asrc + (size_t)N * 8;             // N*8
    int*   ptr  = (int*)(adst + (size_t)N * 8);     // N+1
    int*   col  = ptr + (N + 1);                    // E
    int*   sums = col + E;                          // cdiv(N+1,256)
    float* h3   = (float*)hb;                       // N*10 fp32 (layer 3)

    const int nScan = N + 1;
    const int nChunks = cdiv(nScan, 256);

    // ---- CSR build (once, reused by all 3 layers) ----
    hipMemsetAsync(ptr, 0, (size_t)nScan * sizeof(int), stream);
    hist_kernel<<<cdiv(E, 256), 256, 0, stream>>>(ei, E, ptr);
    scan_chunk_kernel<<<nChunks, 256, 0, stream>>>(ptr, nScan, sums);
    scan_sums_kernel<<<1, 256, 0, stream>>>(sums, nChunks);
    scan_add_kernel<<<nChunks, 256, 0, stream>>>(ptr, nScan, sums);
    scatter_kernel<<<cdiv(E, 256), 256, 0, stream>>>(ei, E, ptr, col);

    // ================= layer 1: 128 -> 8 heads x 16 =================
    gemm_tiled_bf<128, 128, 64, 64, 8><<<cdiv(N, 64), 256, 0, stream>>>(x, W1, hb, N);
    alpha_kernel<bf16, 8, 16><<<cdiv((long)N * 8, 256), 256, 0, stream>>>(hb, as1, ad1, asrc, adst, N);
    agg_ln_kernel<8, 16><<<N, 128, 0, stream>>>(ptr, col, asrc, adst, hb, b1, g1, be1, agg, N);

    // ================= layer 2: 128 -> 4 heads x 16 =================
    gemm_tiled_bf<128, 64, 128, 64, 8><<<cdiv(N, 128), 256, 0, stream>>>(agg, W2, hb, N);
    alpha_kernel<bf16, 4, 16><<<cdiv((long)N * 4, 256), 256, 0, stream>>>(hb, as2, ad2, asrc, adst, N);
    agg_ln_kernel<4, 16><<<N, 64, 0, stream>>>(ptr, col, asrc, adst, hb, b2, g2, be2, agg, N);

    // ================= layer 3: 64 -> 1 head x 10, mean(=identity) ==
    gemm_kernel<64, 10><<<cdiv((long)N * 10, 256), 256, 0, stream>>>(agg, W3, h3, N);
    alpha_kernel<float, 1, 10><<<cdiv(N, 256), 256, 0, stream>>>(h3, as3, ad3, asrc, adst, N);
    agg_csr_l3<<<cdiv(N, 4), 256, 0, stream>>>(ptr, col, asrc, adst, h3, agg, N);
    final_kernel<<<cdiv(N, 256), 256, 0, stream>>>(agg, b3, (float*)d_out, N);
}

// Round 7
// 688.769 us; speedup vs baseline: 30.5742x; 1.3450x over previous
//
#include <hip/hip_runtime.h>
#include <hip/hip_bf16.h>
#include <math.h>

typedef __hip_bfloat16 bf16;

__device__ __forceinline__ float ldf(const float* p, size_t i) { return p[i]; }
__device__ __forceinline__ float ldf(const bf16* p, size_t i) { return __bfloat162float(p[i]); }

// load PF bf16 features (packed) as floats
template<int PF>
__device__ __forceinline__ void ldbf(const bf16* p, float* v) {
    if constexpr (PF == 1) {
        unsigned short u = *reinterpret_cast<const unsigned short*>(p);
        v[0] = __uint_as_float(((unsigned)u) << 16);
    } else {
        unsigned u = *reinterpret_cast<const unsigned*>(p);
        v[0] = __uint_as_float(u << 16);
        v[1] = __uint_as_float(u & 0xffff0000u);
    }
}

// ---------------- naive GEMM (kept for tiny layer 3) ------------------------
template<int K, int M>
__global__ __launch_bounds__(256) void gemm_kernel(
    const float* __restrict__ X, const float* __restrict__ W,
    float* __restrict__ Hout, int N)
{
    int gid = blockIdx.x * 256 + threadIdx.x;
    if (gid >= N * M) return;
    int n = gid / M;
    int m = gid - n * M;
    const float* xr = X + (size_t)n * K;
    float acc = 0.f;
    #pragma unroll 8
    for (int k = 0; k < K; ++k)
        acc += xr[k] * W[k * M + m];
    Hout[gid] = acc;
}

// ---------------- LDS-tiled register-blocked GEMM, bf16 output --------------
template<int K, int M, int BM, int BK, int TM>
__global__ __launch_bounds__(256) void gemm_tiled_bf(
    const float* __restrict__ X, const float* __restrict__ W,
    bf16* __restrict__ Hout, int N)
{
    constexpr int BKP = BK + 4;
    __shared__ float Xs[BM * BKP];
    __shared__ float Ws[BK * M];
    constexpr int NCG = M / 4;
    constexpr int NRG = 256 / NCG;
    static_assert(NRG * TM == BM, "tile mismatch");
    int tid = threadIdx.x;
    int mcol = (tid % NCG) * 4;
    int mrow = (tid / NCG) * TM;
    int r0 = blockIdx.x * BM;

    float acc[TM][4];
    #pragma unroll
    for (int i = 0; i < TM; ++i)
        #pragma unroll
        for (int j = 0; j < 4; ++j) acc[i][j] = 0.f;

    for (int k0 = 0; k0 < K; k0 += BK) {
        constexpr int XF4 = BM * BK / 4;
        for (int f = tid; f < XF4; f += 256) {
            int n = f / (BK / 4);
            int kq = f % (BK / 4);
            int row = r0 + n;
            float4 v = make_float4(0.f, 0.f, 0.f, 0.f);
            if (row < N)
                v = *reinterpret_cast<const float4*>(X + (size_t)row * K + k0 + kq * 4);
            *reinterpret_cast<float4*>(&Xs[n * BKP + kq * 4]) = v;
        }
        constexpr int WF4 = BK * M / 4;
        for (int f = tid; f < WF4; f += 256) {
            int kr = f / (M / 4);
            int mq = f % (M / 4);
            *reinterpret_cast<float4*>(&Ws[kr * M + mq * 4]) =
                *reinterpret_cast<const float4*>(W + (size_t)(k0 + kr) * M + mq * 4);
        }
        __syncthreads();
        #pragma unroll
        for (int k = 0; k < BK; ++k) {
            float xv[TM];
            #pragma unroll
            for (int i = 0; i < TM; ++i) xv[i] = Xs[(mrow + i) * BKP + k];
            float4 wv = *reinterpret_cast<const float4*>(&Ws[k * M + mcol]);
            #pragma unroll
            for (int i = 0; i < TM; ++i) {
                acc[i][0] += xv[i] * wv.x;
                acc[i][1] += xv[i] * wv.y;
                acc[i][2] += xv[i] * wv.z;
                acc[i][3] += xv[i] * wv.w;
            }
        }
        __syncthreads();
    }
    #pragma unroll
    for (int i = 0; i < TM; ++i) {
        int row = r0 + mrow + i;
        if (row < N) {
            alignas(8) bf16 pk[4];
            #pragma unroll
            for (int j = 0; j < 4; ++j) pk[j] = __float2bfloat16(acc[i][j]);
            *reinterpret_cast<uint2*>(Hout + (size_t)row * M + mcol) =
                *reinterpret_cast<uint2*>(pk);
        }
    }
}

// ---------------- alpha_src/alpha_dst: [N,H] = sum_f h[n,hd,f]*a[hd,f] ------
template<typename T, int H, int F>
__global__ __launch_bounds__(256) void alpha_kernel(
    const T* __restrict__ h, const float* __restrict__ av_src,
    const float* __restrict__ av_dst, float* __restrict__ asrc,
    float* __restrict__ adst, int N)
{
    int gid = blockIdx.x * 256 + threadIdx.x;
    if (gid >= N * H) return;
    int n = gid / H;
    int hd = gid - n * H;
    const T* hr = h + (size_t)n * (H * F) + hd * F;
    float s1 = 0.f, s2 = 0.f;
    #pragma unroll
    for (int f = 0; f < F; ++f) {
        float v = ldf(hr, f);
        s1 += v * av_src[hd * F + f];
        s2 += v * av_dst[hd * F + f];
    }
    asrc[gid] = s1;
    adst[gid] = s2;
}

// ---------------- CSR build: histogram -> 2-level scan -> scatter -----------
__global__ __launch_bounds__(256) void hist_kernel(
    const int* __restrict__ ei, int E, int* __restrict__ ptr)
{
    int i = blockIdx.x * 256 + threadIdx.x;
    if (i >= E) return;
    atomicAdd(&ptr[ei[E + i] + 1], 1);
}

__global__ __launch_bounds__(256) void scan_chunk_kernel(
    int* __restrict__ p, int n, int* __restrict__ sums)
{
    __shared__ int sm[256];
    int tid = threadIdx.x;
    int i = blockIdx.x * 256 + tid;
    sm[tid] = (i < n) ? p[i] : 0;
    __syncthreads();
    #pragma unroll
    for (int o = 1; o < 256; o <<= 1) {
        int t = (tid >= o) ? sm[tid - o] : 0;
        __syncthreads();
        sm[tid] += t;
        __syncthreads();
    }
    if (i < n) p[i] = sm[tid];
    if (tid == 255) sums[blockIdx.x] = sm[255];
}

__global__ __launch_bounds__(256) void scan_sums_kernel(int* __restrict__ s, int nc)
{
    __shared__ int sm[256];
    int tid = threadIdx.x;
    int carry = 0;
    for (int base = 0; base < nc; base += 256) {
        int i = base + tid;
        sm[tid] = (i < nc) ? s[i] : 0;
        __syncthreads();
        #pragma unroll
        for (int o = 1; o < 256; o <<= 1) {
            int t = (tid >= o) ? sm[tid - o] : 0;
            __syncthreads();
            sm[tid] += t;
            __syncthreads();
        }
        if (i < nc) s[i] = sm[tid] + carry;
        carry += sm[255];
        __syncthreads();
    }
}

__global__ __launch_bounds__(256) void scan_add_kernel(
    int* __restrict__ p, int n, const int* __restrict__ sums)
{
    int c = blockIdx.x;
    if (c == 0) return;
    int i = c * 256 + threadIdx.x;
    if (i < n) p[i] += sums[c - 1];
}

// after scatter, ptr[d] becomes END of node d; start = (d?ptr[d-1]:0)
__global__ __launch_bounds__(256) void scatter_kernel(
    const int* __restrict__ ei, int E, int* __restrict__ ptr,
    int* __restrict__ col)
{
    int i = blockIdx.x * 256 + threadIdx.x;
    if (i >= E) return;
    int src = ei[i];
    int dst = ei[E + i];
    int pos = atomicAdd(&ptr[dst], 1);
    col[pos] = src;
}

// ------- CSR agg + bias + LN + ELU fused: one WAVE per dst node -------------
// 64 lanes; lane owns PF = M/64 packed features (same head). Edge loop
// unrolled x4 with independent accumulator chains for memory-level parallelism.
template<int H, int F>
__global__ __launch_bounds__(64) void agg_ln_kernel(
    const int* __restrict__ ptr, const int* __restrict__ col,
    const float* __restrict__ asrc, const float* __restrict__ adst,
    const bf16* __restrict__ hb, const float* __restrict__ bias,
    const float* __restrict__ g, const float* __restrict__ be,
    float* __restrict__ out, int N)
{
    constexpr int M = H * F;
    constexpr int PF = M / 64;
    int d = blockIdx.x;
    int lane = threadIdx.x;
    int f0 = lane * PF;
    int hd = f0 / F;
    int start = (d == 0) ? 0 : ptr[d - 1];
    int end = ptr[d];
    float adst_h = adst[d * H + hd];

    float ac0[PF], ac1[PF], ac2[PF], ac3[PF];
    float dn0, dn1 = 0.f, dn2 = 0.f, dn3 = 0.f;
    #pragma unroll
    for (int p = 0; p < PF; ++p) { ac1[p] = 0.f; ac2[p] = 0.f; ac3[p] = 0.f; }

    { // self loop -> chain 0
        float lg = asrc[d * H + hd] + adst_h;
        lg = lg > 0.f ? lg : 0.2f * lg;
        float w = __expf(lg);
        float v[PF];
        ldbf<PF>(hb + (size_t)d * M + f0, v);
        #pragma unroll
        for (int p = 0; p < PF; ++p) ac0[p] = w * v[p];
        dn0 = w;
    }

    int e = start;
    for (; e + 4 <= end; e += 4) {
        int s0 = col[e + 0], s1 = col[e + 1], s2 = col[e + 2], s3 = col[e + 3];
        float l0 = asrc[s0 * H + hd];
        float l1 = asrc[s1 * H + hd];
        float l2 = asrc[s2 * H + hd];
        float l3 = asrc[s3 * H + hd];
        float v0[PF], v1[PF], v2[PF], v3[PF];
        ldbf<PF>(hb + (size_t)s0 * M + f0, v0);
        ldbf<PF>(hb + (size_t)s1 * M + f0, v1);
        ldbf<PF>(hb + (size_t)s2 * M + f0, v2);
        ldbf<PF>(hb + (size_t)s3 * M + f0, v3);
        l0 += adst_h; l0 = l0 > 0.f ? l0 : 0.2f * l0; float w0 = __expf(l0);
        l1 += adst_h; l1 = l1 > 0.f ? l1 : 0.2f * l1; float w1 = __expf(l1);
        l2 += adst_h; l2 = l2 > 0.f ? l2 : 0.2f * l2; float w2 = __expf(l2);
        l3 += adst_h; l3 = l3 > 0.f ? l3 : 0.2f * l3; float w3 = __expf(l3);
        #pragma unroll
        for (int p = 0; p < PF; ++p) {
            ac0[p] += w0 * v0[p];
            ac1[p] += w1 * v1[p];
            ac2[p] += w2 * v2[p];
            ac3[p] += w3 * v3[p];
        }
        dn0 += w0; dn1 += w1; dn2 += w2; dn3 += w3;
    }
    for (; e < end; ++e) {
        int s = col[e];
        float lg = asrc[s * H + hd] + adst_h;
        lg = lg > 0.f ? lg : 0.2f * lg;
        float w = __expf(lg);
        float v[PF];
        ldbf<PF>(hb + (size_t)s * M + f0, v);
        #pragma unroll
        for (int p = 0; p < PF; ++p) ac0[p] += w * v[p];
        dn0 += w;
    }

    float den = dn0 + dn1 + dn2 + dn3;
    float rden = 1.f / (den + 1e-16f);
    float o[PF];
    float sm1 = 0.f, sm2 = 0.f;
    #pragma unroll
    for (int p = 0; p < PF; ++p) {
        o[p] = (ac0[p] + ac1[p] + ac2[p] + ac3[p]) * rden + bias[f0 + p];
        sm1 += o[p];
        sm2 += o[p] * o[p];
    }
    #pragma unroll
    for (int off = 32; off >= 1; off >>= 1) {
        sm1 += __shfl_xor(sm1, off, 64);
        sm2 += __shfl_xor(sm2, off, 64);
    }
    float mu = sm1 * (1.f / M);
    float var = sm2 * (1.f / M) - mu * mu;
    float inv = rsqrtf(var + 1e-5f);
    float y[PF];
    #pragma unroll
    for (int p = 0; p < PF; ++p) {
        float t = (o[p] - mu) * inv * g[f0 + p] + be[f0 + p];
        y[p] = t > 0.f ? t : expm1f(t);
    }
    if constexpr (PF == 2) {
        *reinterpret_cast<float2*>(out + (size_t)d * M + f0) = make_float2(y[0], y[1]);
    } else {
        out[(size_t)d * M + f0] = y[0];
    }
}

// ---------------- layer-3 aggregation: one wave per dst, H=1, F=10 ----------
__global__ __launch_bounds__(256) void agg_csr_l3(
    const int* __restrict__ ptr, const int* __restrict__ col,
    const float* __restrict__ asrc, const float* __restrict__ adst,
    const float* __restrict__ h, float* __restrict__ out, int N)
{
    int wave = threadIdx.x >> 6;
    int lane = threadIdx.x & 63;
    int d = blockIdx.x * 4 + wave;
    if (d >= N) return;
    int start = (d == 0) ? 0 : ptr[d - 1];
    int end = ptr[d];
    float adst_d = adst[d];
    float lg = asrc[d] + adst_d;
    lg = lg > 0.f ? lg : 0.2f * lg;
    float w = __expf(lg);
    bool act = lane < 10;
    float a0 = act ? w * h[(size_t)d * 10 + lane] : 0.f;
    float a1 = 0.f, a2 = 0.f, a3 = 0.f;
    float d0 = w, d1 = 0.f, d2 = 0.f, d3 = 0.f;
    int e = start;
    for (; e + 4 <= end; e += 4) {
        int s0 = col[e + 0], s1 = col[e + 1], s2 = col[e + 2], s3 = col[e + 3];
        float l0 = asrc[s0], l1 = asrc[s1], l2 = asrc[s2], l3 = asrc[s3];
        float v0 = act ? h[(size_t)s0 * 10 + lane] : 0.f;
        float v1 = act ? h[(size_t)s1 * 10 + lane] : 0.f;
        float v2 = act ? h[(size_t)s2 * 10 + lane] : 0.f;
        float v3 = act ? h[(size_t)s3 * 10 + lane] : 0.f;
        l0 += adst_d; l0 = l0 > 0.f ? l0 : 0.2f * l0; float w0 = __expf(l0);
        l1 += adst_d; l1 = l1 > 0.f ? l1 : 0.2f * l1; float w1 = __expf(l1);
        l2 += adst_d; l2 = l2 > 0.f ? l2 : 0.2f * l2; float w2 = __expf(l2);
        l3 += adst_d; l3 = l3 > 0.f ? l3 : 0.2f * l3; float w3 = __expf(l3);
        a0 += w0 * v0; a1 += w1 * v1; a2 += w2 * v2; a3 += w3 * v3;
        d0 += w0; d1 += w1; d2 += w2; d3 += w3;
    }
    for (; e < end; ++e) {
        int s = col[e];
        float l = asrc[s] + adst_d;
        l = l > 0.f ? l : 0.2f * l;
        float ww = __expf(l);
        if (act) a0 += ww * h[(size_t)s * 10 + lane];
        d0 += ww;
    }
    float den = d0 + d1 + d2 + d3;
    if (act) out[(size_t)d * 10 + lane] = (a0 + a1 + a2 + a3) / (den + 1e-16f);
}

// ---------------- final: +bias then log_softmax over 10, write fp32 ---------
__global__ __launch_bounds__(256) void final_kernel(
    const float* __restrict__ agg, const float* __restrict__ b3,
    float* __restrict__ out, int N)
{
    int n = blockIdx.x * 256 + threadIdx.x;
    if (n >= N) return;
    float v[10];
    float mx = -1e30f;
    #pragma unroll
    for (int j = 0; j < 10; ++j) {
        v[j] = agg[(size_t)n * 10 + j] + b3[j];
        mx = fmaxf(mx, v[j]);
    }
    float se = 0.f;
    #pragma unroll
    for (int j = 0; j < 10; ++j) se += __expf(v[j] - mx);
    float ls = mx + logf(se);
    #pragma unroll
    for (int j = 0; j < 10; ++j)
        out[(size_t)n * 10 + j] = v[j] - ls;
}

static inline int cdiv(long a, long b) { return (int)((a + b - 1) / b); }

extern "C" void kernel_launch(void* const* d_in, const int* in_sizes, int n_in,
                              void* d_out, int out_size, void* d_ws, size_t ws_size,
                              hipStream_t stream)
{
    const float* x   = (const float*)d_in[0];
    const int*   ei  = (const int*)d_in[1];
    const float* W1  = (const float*)d_in[2];
    const float* as1 = (const float*)d_in[3];
    const float* ad1 = (const float*)d_in[4];
    const float* b1  = (const float*)d_in[5];
    const float* g1  = (const float*)d_in[6];
    const float* be1 = (const float*)d_in[7];
    const float* W2  = (const float*)d_in[8];
    const float* as2 = (const float*)d_in[9];
    const float* ad2 = (const float*)d_in[10];
    const float* b2  = (const float*)d_in[11];
    const float* g2  = (const float*)d_in[12];
    const float* be2 = (const float*)d_in[13];
    const float* W3  = (const float*)d_in[14];
    const float* as3 = (const float*)d_in[15];
    const float* ad3 = (const float*)d_in[16];
    const float* b3  = (const float*)d_in[17];

    const int N = in_sizes[0] / 128;
    const int E = in_sizes[1] / 2;

    bf16*  hb   = (bf16*)d_ws;                      // N*128 bf16 (fp32 N*10 for L3)
    float* agg  = (float*)(hb + (size_t)N * 128);   // N*128 fp32
    float* asrc = agg + (size_t)N * 128;            // N*8
    float* adst = asrc + (size_t)N * 8;             // N*8
    int*   ptr  = (int*)(adst + (size_t)N * 8);     // N+1
    int*   col  = ptr + (N + 1);                    // E
    int*   sums = col + E;                          // cdiv(N+1,256)
    float* h3   = (float*)hb;                       // N*10 fp32 (layer 3)

    const int nScan = N + 1;
    const int nChunks = cdiv(nScan, 256);

    // ---- CSR build (once, reused by all 3 layers) ----
    hipMemsetAsync(ptr, 0, (size_t)nScan * sizeof(int), stream);
    hist_kernel<<<cdiv(E, 256), 256, 0, stream>>>(ei, E, ptr);
    scan_chunk_kernel<<<nChunks, 256, 0, stream>>>(ptr, nScan, sums);
    scan_sums_kernel<<<1, 256, 0, stream>>>(sums, nChunks);
    scan_add_kernel<<<nChunks, 256, 0, stream>>>(ptr, nScan, sums);
    scatter_kernel<<<cdiv(E, 256), 256, 0, stream>>>(ei, E, ptr, col);

    // ================= layer 1: 128 -> 8 heads x 16 =================
    gemm_tiled_bf<128, 128, 64, 64, 8><<<cdiv(N, 64), 256, 0, stream>>>(x, W1, hb, N);
    alpha_kernel<bf16, 8, 16><<<cdiv((long)N * 8, 256), 256, 0, stream>>>(hb, as1, ad1, asrc, adst, N);
    agg_ln_kernel<8, 16><<<N, 64, 0, stream>>>(ptr, col, asrc, adst, hb, b1, g1, be1, agg, N);

    // ================= layer 2: 128 -> 4 heads x 16 =================
    gemm_tiled_bf<128, 64, 128, 64, 8><<<cdiv(N, 128), 256, 0, stream>>>(agg, W2, hb, N);
    alpha_kernel<bf16, 4, 16><<<cdiv((long)N * 4, 256), 256, 0, stream>>>(hb, as2, ad2, asrc, adst, N);
    agg_ln_kernel<4, 16><<<N, 64, 0, stream>>>(ptr, col, asrc, adst, hb, b2, g2, be2, agg, N);

    // ================= layer 3: 64 -> 1 head x 10, mean(=identity) ==
    gemm_kernel<64, 10><<<cdiv((long)N * 10, 256), 256, 0, stream>>>(agg, W3, h3, N);
    alpha_kernel<float, 1, 10><<<cdiv(N, 256), 256, 0, stream>>>(h3, as3, ad3, asrc, adst, N);
    agg_csr_l3<<<cdiv(N, 4), 256, 0, stream>>>(ptr, col, asrc, adst, h3, agg, N);
    final_kernel<<<cdiv(N, 256), 256, 0, stream>>>(agg, b3, (float*)d_out, N);
}

// Round 8
// 530.764 us; speedup vs baseline: 39.6760x; 1.2977x over previous
//
#include <hip/hip_runtime.h>
#include <hip/hip_bf16.h>
#include <math.h>

typedef __hip_bfloat16 bf16;

__device__ __forceinline__ float ldf(const float* p, size_t i) { return p[i]; }
__device__ __forceinline__ float ldf(const bf16* p, size_t i) { return __bfloat162float(p[i]); }

// load PF bf16 features (packed) as floats
template<int PF>
__device__ __forceinline__ void ldbf(const bf16* p, float* v) {
    if constexpr (PF == 1) {
        unsigned short u = *reinterpret_cast<const unsigned short*>(p);
        v[0] = __uint_as_float(((unsigned)u) << 16);
    } else {
        unsigned u = *reinterpret_cast<const unsigned*>(p);
        v[0] = __uint_as_float(u << 16);
        v[1] = __uint_as_float(u & 0xffff0000u);
    }
}

// ---------------- naive GEMM (kept for tiny layer 3) ------------------------
template<int K, int M>
__global__ __launch_bounds__(256) void gemm_kernel(
    const float* __restrict__ X, const float* __restrict__ W,
    float* __restrict__ Hout, int N)
{
    int gid = blockIdx.x * 256 + threadIdx.x;
    if (gid >= N * M) return;
    int n = gid / M;
    int m = gid - n * M;
    const float* xr = X + (size_t)n * K;
    float acc = 0.f;
    #pragma unroll 8
    for (int k = 0; k < K; ++k)
        acc += xr[k] * W[k * M + m];
    Hout[gid] = acc;
}

// ---------------- LDS-tiled register-blocked GEMM, bf16 output --------------
template<int K, int M, int BM, int BK, int TM>
__global__ __launch_bounds__(256) void gemm_tiled_bf(
    const float* __restrict__ X, const float* __restrict__ W,
    bf16* __restrict__ Hout, int N)
{
    constexpr int BKP = BK + 4;
    __shared__ float Xs[BM * BKP];
    __shared__ float Ws[BK * M];
    constexpr int NCG = M / 4;
    constexpr int NRG = 256 / NCG;
    static_assert(NRG * TM == BM, "tile mismatch");
    int tid = threadIdx.x;
    int mcol = (tid % NCG) * 4;
    int mrow = (tid / NCG) * TM;
    int r0 = blockIdx.x * BM;

    float acc[TM][4];
    #pragma unroll
    for (int i = 0; i < TM; ++i)
        #pragma unroll
        for (int j = 0; j < 4; ++j) acc[i][j] = 0.f;

    for (int k0 = 0; k0 < K; k0 += BK) {
        constexpr int XF4 = BM * BK / 4;
        for (int f = tid; f < XF4; f += 256) {
            int n = f / (BK / 4);
            int kq = f % (BK / 4);
            int row = r0 + n;
            float4 v = make_float4(0.f, 0.f, 0.f, 0.f);
            if (row < N)
                v = *reinterpret_cast<const float4*>(X + (size_t)row * K + k0 + kq * 4);
            *reinterpret_cast<float4*>(&Xs[n * BKP + kq * 4]) = v;
        }
        constexpr int WF4 = BK * M / 4;
        for (int f = tid; f < WF4; f += 256) {
            int kr = f / (M / 4);
            int mq = f % (M / 4);
            *reinterpret_cast<float4*>(&Ws[kr * M + mq * 4]) =
                *reinterpret_cast<const float4*>(W + (size_t)(k0 + kr) * M + mq * 4);
        }
        __syncthreads();
        #pragma unroll
        for (int k = 0; k < BK; ++k) {
            float xv[TM];
            #pragma unroll
            for (int i = 0; i < TM; ++i) xv[i] = Xs[(mrow + i) * BKP + k];
            float4 wv = *reinterpret_cast<const float4*>(&Ws[k * M + mcol]);
            #pragma unroll
            for (int i = 0; i < TM; ++i) {
                acc[i][0] += xv[i] * wv.x;
                acc[i][1] += xv[i] * wv.y;
                acc[i][2] += xv[i] * wv.z;
                acc[i][3] += xv[i] * wv.w;
            }
        }
        __syncthreads();
    }
    #pragma unroll
    for (int i = 0; i < TM; ++i) {
        int row = r0 + mrow + i;
        if (row < N) {
            alignas(8) bf16 pk[4];
            #pragma unroll
            for (int j = 0; j < 4; ++j) pk[j] = __float2bfloat16(acc[i][j]);
            *reinterpret_cast<uint2*>(Hout + (size_t)row * M + mcol) =
                *reinterpret_cast<uint2*>(pk);
        }
    }
}

// ---------------- alpha_src/alpha_dst: [N,H] = sum_f h[n,hd,f]*a[hd,f] ------
template<typename T, int H, int F>
__global__ __launch_bounds__(256) void alpha_kernel(
    const T* __restrict__ h, const float* __restrict__ av_src,
    const float* __restrict__ av_dst, float* __restrict__ asrc,
    float* __restrict__ adst, int N)
{
    int gid = blockIdx.x * 256 + threadIdx.x;
    if (gid >= N * H) return;
    int n = gid / H;
    int hd = gid - n * H;
    const T* hr = h + (size_t)n * (H * F) + hd * F;
    float s1 = 0.f, s2 = 0.f;
    #pragma unroll
    for (int f = 0; f < F; ++f) {
        float v = ldf(hr, f);
        s1 += v * av_src[hd * F + f];
        s2 += v * av_dst[hd * F + f];
    }
    asrc[gid] = s1;
    adst[gid] = s2;
}

// ============== atomic-free CSR build: counting sort by dst ==================
// Coarse buckets: NB=256, DPB dsts/bucket. Edge chunks: CH=4096 edges/block.
// A: per-block LDS histogram over buckets  -> histM[blk][256] (coalesced)
// B1: per-bucket exclusive scan over blocks -> offT[b][blk] + btot[b]
// B2: scan bucket totals -> bbase[257]
// C: scatter (src,dst) pairs bucket-grouped; block-exclusive write ranges
// D: per-bucket fine CSR: LDS hist over DPB dsts, scan, write ptr + col
//    (col writes stay inside the bucket's exclusive region -> no false sharing)

#define CSR_CH 4096

__global__ __launch_bounds__(256) void csr_hist(
    const int* __restrict__ ei, int E, int DPB, int* __restrict__ histM)
{
    __shared__ int cnt[256];
    int tid = threadIdx.x;
    cnt[tid] = 0;
    __syncthreads();
    int e0 = blockIdx.x * CSR_CH;
    int e1 = min(E, e0 + CSR_CH);
    for (int e = e0 + tid; e < e1; e += 256)
        atomicAdd(&cnt[ei[E + e] / DPB], 1);
    __syncthreads();
    histM[blockIdx.x * 256 + tid] = cnt[tid];
}

__global__ __launch_bounds__(256) void csr_colscan(
    const int* __restrict__ histM, int NBLK,
    int* __restrict__ offT, int* __restrict__ btot)
{
    __shared__ int sm[512];
    int b = blockIdx.x;
    int tid = threadIdx.x;
    int i0 = tid, i1 = tid + 256;
    sm[i0] = (i0 < NBLK) ? histM[i0 * 256 + b] : 0;
    sm[i1] = (i1 < NBLK) ? histM[i1 * 256 + b] : 0;
    __syncthreads();
    #pragma unroll
    for (int o = 1; o < 512; o <<= 1) {
        int t0 = (i0 >= o) ? sm[i0 - o] : 0;
        int t1 = (i1 >= o) ? sm[i1 - o] : 0;
        __syncthreads();
        sm[i0] += t0; sm[i1] += t1;
        __syncthreads();
    }
    if (i0 < NBLK) offT[b * NBLK + i0] = (i0 == 0) ? 0 : sm[i0 - 1];
    if (i1 < NBLK) offT[b * NBLK + i1] = sm[i1 - 1];
    if (tid == 0) btot[b] = sm[511];
}

__global__ __launch_bounds__(256) void csr_basescan(
    const int* __restrict__ btot, int* __restrict__ bbase)
{
    __shared__ int sm[256];
    int tid = threadIdx.x;
    int v = btot[tid];
    sm[tid] = v;
    __syncthreads();
    #pragma unroll
    for (int o = 1; o < 256; o <<= 1) {
        int t = (tid >= o) ? sm[tid - o] : 0;
        __syncthreads();
        sm[tid] += t;
        __syncthreads();
    }
    bbase[tid] = sm[tid] - v;            // exclusive
    if (tid == 255) bbase[256] = sm[255];
}

__global__ __launch_bounds__(256) void csr_pair_scatter(
    const int* __restrict__ ei, int E, int DPB,
    const int* __restrict__ offT, int NBLK, const int* __restrict__ bbase,
    int2* __restrict__ pairs)
{
    __shared__ int cnt[256];
    int tid = threadIdx.x;
    int blk = blockIdx.x;
    cnt[tid] = bbase[tid] + offT[tid * NBLK + blk];
    __syncthreads();
    int e0 = blk * CSR_CH;
    int e1 = min(E, e0 + CSR_CH);
    for (int e = e0 + tid; e < e1; e += 256) {
        int s = ei[e];
        int d = ei[E + e];
        int pos = atomicAdd(&cnt[d / DPB], 1);
        pairs[pos] = make_int2(s, d);
    }
}

__global__ __launch_bounds__(256) void csr_fine(
    const int2* __restrict__ pairs, const int* __restrict__ bbase,
    int DPB, int N, int* __restrict__ ptr, int* __restrict__ col)
{
    __shared__ int sm[512];
    __shared__ int off[512];
    int b = blockIdx.x;
    int tid = threadIdx.x;
    int base = bbase[b];
    int tot = bbase[b + 1] - base;
    int d0 = b * DPB;
    int i0 = tid, i1 = tid + 256;
    sm[i0] = 0; sm[i1] = 0;
    __syncthreads();
    for (int i = tid; i < tot; i += 256)
        atomicAdd(&sm[pairs[base + i].y - d0], 1);
    __syncthreads();
    #pragma unroll
    for (int o = 1; o < 512; o <<= 1) {
        int t0 = (i0 >= o) ? sm[i0 - o] : 0;
        int t1 = (i1 >= o) ? sm[i1 - o] : 0;
        __syncthreads();
        sm[i0] += t0; sm[i1] += t1;
        __syncthreads();
    }
    off[i0] = base + ((i0 == 0) ? 0 : sm[i0 - 1]);
    off[i1] = base + sm[i1 - 1];
    if (i0 < DPB && d0 + i0 < N) ptr[d0 + i0] = base + sm[i0];
    if (i1 < DPB && d0 + i1 < N) ptr[d0 + i1] = base + sm[i1];
    __syncthreads();
    for (int i = tid; i < tot; i += 256) {
        int2 p = pairs[base + i];
        int pos = atomicAdd(&off[p.y - d0], 1);
        col[pos] = p.x;
    }
}

// ------- CSR agg + bias + LN + ELU fused: one WAVE per dst node -------------
template<int H, int F>
__global__ __launch_bounds__(64) void agg_ln_kernel(
    const int* __restrict__ ptr, const int* __restrict__ col,
    const float* __restrict__ asrc, const float* __restrict__ adst,
    const bf16* __restrict__ hb, const float* __restrict__ bias,
    const float* __restrict__ g, const float* __restrict__ be,
    float* __restrict__ out, int N)
{
    constexpr int M = H * F;
    constexpr int PF = M / 64;
    int d = blockIdx.x;
    int lane = threadIdx.x;
    int f0 = lane * PF;
    int hd = f0 / F;
    int start = (d == 0) ? 0 : ptr[d - 1];
    int end = ptr[d];
    float adst_h = adst[d * H + hd];

    float ac0[PF], ac1[PF], ac2[PF], ac3[PF];
    float dn0, dn1 = 0.f, dn2 = 0.f, dn3 = 0.f;
    #pragma unroll
    for (int p = 0; p < PF; ++p) { ac1[p] = 0.f; ac2[p] = 0.f; ac3[p] = 0.f; }

    { // self loop -> chain 0
        float lg = asrc[d * H + hd] + adst_h;
        lg = lg > 0.f ? lg : 0.2f * lg;
        float w = __expf(lg);
        float v[PF];
        ldbf<PF>(hb + (size_t)d * M + f0, v);
        #pragma unroll
        for (int p = 0; p < PF; ++p) ac0[p] = w * v[p];
        dn0 = w;
    }

    int e = start;
    for (; e + 4 <= end; e += 4) {
        int s0 = col[e + 0], s1 = col[e + 1], s2 = col[e + 2], s3 = col[e + 3];
        float l0 = asrc[s0 * H + hd];
        float l1 = asrc[s1 * H + hd];
        float l2 = asrc[s2 * H + hd];
        float l3 = asrc[s3 * H + hd];
        float v0[PF], v1[PF], v2[PF], v3[PF];
        ldbf<PF>(hb + (size_t)s0 * M + f0, v0);
        ldbf<PF>(hb + (size_t)s1 * M + f0, v1);
        ldbf<PF>(hb + (size_t)s2 * M + f0, v2);
        ldbf<PF>(hb + (size_t)s3 * M + f0, v3);
        l0 += adst_h; l0 = l0 > 0.f ? l0 : 0.2f * l0; float w0 = __expf(l0);
        l1 += adst_h; l1 = l1 > 0.f ? l1 : 0.2f * l1; float w1 = __expf(l1);
        l2 += adst_h; l2 = l2 > 0.f ? l2 : 0.2f * l2; float w2 = __expf(l2);
        l3 += adst_h; l3 = l3 > 0.f ? l3 : 0.2f * l3; float w3 = __expf(l3);
        #pragma unroll
        for (int p = 0; p < PF; ++p) {
            ac0[p] += w0 * v0[p];
            ac1[p] += w1 * v1[p];
            ac2[p] += w2 * v2[p];
            ac3[p] += w3 * v3[p];
        }
        dn0 += w0; dn1 += w1; dn2 += w2; dn3 += w3;
    }
    for (; e < end; ++e) {
        int s = col[e];
        float lg = asrc[s * H + hd] + adst_h;
        lg = lg > 0.f ? lg : 0.2f * lg;
        float w = __expf(lg);
        float v[PF];
        ldbf<PF>(hb + (size_t)s * M + f0, v);
        #pragma unroll
        for (int p = 0; p < PF; ++p) ac0[p] += w * v[p];
        dn0 += w;
    }

    float den = dn0 + dn1 + dn2 + dn3;
    float rden = 1.f / (den + 1e-16f);
    float o[PF];
    float sm1 = 0.f, sm2 = 0.f;
    #pragma unroll
    for (int p = 0; p < PF; ++p) {
        o[p] = (ac0[p] + ac1[p] + ac2[p] + ac3[p]) * rden + bias[f0 + p];
        sm1 += o[p];
        sm2 += o[p] * o[p];
    }
    #pragma unroll
    for (int off = 32; off >= 1; off >>= 1) {
        sm1 += __shfl_xor(sm1, off, 64);
        sm2 += __shfl_xor(sm2, off, 64);
    }
    float mu = sm1 * (1.f / M);
    float var = sm2 * (1.f / M) - mu * mu;
    float inv = rsqrtf(var + 1e-5f);
    float y[PF];
    #pragma unroll
    for (int p = 0; p < PF; ++p) {
        float t = (o[p] - mu) * inv * g[f0 + p] + be[f0 + p];
        y[p] = t > 0.f ? t : expm1f(t);
    }
    if constexpr (PF == 2) {
        *reinterpret_cast<float2*>(out + (size_t)d * M + f0) = make_float2(y[0], y[1]);
    } else {
        out[(size_t)d * M + f0] = y[0];
    }
}

// ---------------- layer-3 aggregation: one wave per dst, H=1, F=10 ----------
__global__ __launch_bounds__(256) void agg_csr_l3(
    const int* __restrict__ ptr, const int* __restrict__ col,
    const float* __restrict__ asrc, const float* __restrict__ adst,
    const float* __restrict__ h, float* __restrict__ out, int N)
{
    int wave = threadIdx.x >> 6;
    int lane = threadIdx.x & 63;
    int d = blockIdx.x * 4 + wave;
    if (d >= N) return;
    int start = (d == 0) ? 0 : ptr[d - 1];
    int end = ptr[d];
    float adst_d = adst[d];
    float lg = asrc[d] + adst_d;
    lg = lg > 0.f ? lg : 0.2f * lg;
    float w = __expf(lg);
    bool act = lane < 10;
    float a0 = act ? w * h[(size_t)d * 10 + lane] : 0.f;
    float a1 = 0.f, a2 = 0.f, a3 = 0.f;
    float d0 = w, d1 = 0.f, d2 = 0.f, d3 = 0.f;
    int e = start;
    for (; e + 4 <= end; e += 4) {
        int s0 = col[e + 0], s1 = col[e + 1], s2 = col[e + 2], s3 = col[e + 3];
        float l0 = asrc[s0], l1 = asrc[s1], l2 = asrc[s2], l3 = asrc[s3];
        float v0 = act ? h[(size_t)s0 * 10 + lane] : 0.f;
        float v1 = act ? h[(size_t)s1 * 10 + lane] : 0.f;
        float v2 = act ? h[(size_t)s2 * 10 + lane] : 0.f;
        float v3 = act ? h[(size_t)s3 * 10 + lane] : 0.f;
        l0 += adst_d; l0 = l0 > 0.f ? l0 : 0.2f * l0; float w0 = __expf(l0);
        l1 += adst_d; l1 = l1 > 0.f ? l1 : 0.2f * l1; float w1 = __expf(l1);
        l2 += adst_d; l2 = l2 > 0.f ? l2 : 0.2f * l2; float w2 = __expf(l2);
        l3 += adst_d; l3 = l3 > 0.f ? l3 : 0.2f * l3; float w3 = __expf(l3);
        a0 += w0 * v0; a1 += w1 * v1; a2 += w2 * v2; a3 += w3 * v3;
        d0 += w0; d1 += w1; d2 += w2; d3 += w3;
    }
    for (; e < end; ++e) {
        int s = col[e];
        float l = asrc[s] + adst_d;
        l = l > 0.f ? l : 0.2f * l;
        float ww = __expf(l);
        if (act) a0 += ww * h[(size_t)s * 10 + lane];
        d0 += ww;
    }
    float den = d0 + d1 + d2 + d3;
    if (act) out[(size_t)d * 10 + lane] = (a0 + a1 + a2 + a3) / (den + 1e-16f);
}

// ---------------- final: +bias then log_softmax over 10, write fp32 ---------
__global__ __launch_bounds__(256) void final_kernel(
    const float* __restrict__ agg, const float* __restrict__ b3,
    float* __restrict__ out, int N)
{
    int n = blockIdx.x * 256 + threadIdx.x;
    if (n >= N) return;
    float v[10];
    float mx = -1e30f;
    #pragma unroll
    for (int j = 0; j < 10; ++j) {
        v[j] = agg[(size_t)n * 10 + j] + b3[j];
        mx = fmaxf(mx, v[j]);
    }
    float se = 0.f;
    #pragma unroll
    for (int j = 0; j < 10; ++j) se += __expf(v[j] - mx);
    float ls = mx + logf(se);
    #pragma unroll
    for (int j = 0; j < 10; ++j)
        out[(size_t)n * 10 + j] = v[j] - ls;
}

static inline int cdiv(long a, long b) { return (int)((a + b - 1) / b); }

extern "C" void kernel_launch(void* const* d_in, const int* in_sizes, int n_in,
                              void* d_out, int out_size, void* d_ws, size_t ws_size,
                              hipStream_t stream)
{
    const float* x   = (const float*)d_in[0];
    const int*   ei  = (const int*)d_in[1];
    const float* W1  = (const float*)d_in[2];
    const float* as1 = (const float*)d_in[3];
    const float* ad1 = (const float*)d_in[4];
    const float* b1  = (const float*)d_in[5];
    const float* g1  = (const float*)d_in[6];
    const float* be1 = (const float*)d_in[7];
    const float* W2  = (const float*)d_in[8];
    const float* as2 = (const float*)d_in[9];
    const float* ad2 = (const float*)d_in[10];
    const float* b2  = (const float*)d_in[11];
    const float* g2  = (const float*)d_in[12];
    const float* be2 = (const float*)d_in[13];
    const float* W3  = (const float*)d_in[14];
    const float* as3 = (const float*)d_in[15];
    const float* ad3 = (const float*)d_in[16];
    const float* b3  = (const float*)d_in[17];

    const int N = in_sizes[0] / 128;
    const int E = in_sizes[1] / 2;

    const int DPB  = cdiv(N, 256);         // dsts per bucket
    const int NBLK = cdiv(E, CSR_CH);      // edge chunks (must be <= 512)

    bf16*  hb    = (bf16*)d_ws;                      // N*128 bf16
    float* agg   = (float*)(hb + (size_t)N * 128);   // N*128 fp32
    float* asrc  = agg + (size_t)N * 128;            // N*8
    float* adst  = asrc + (size_t)N * 8;             // N*8
    int2*  pairs = (int2*)(adst + (size_t)N * 8);    // E pairs (8B aligned)
    int*   col   = (int*)(pairs + E);                // E
    int*   ptr   = col + E;                          // N+1
    int*   histM = ptr + (N + 1);                    // NBLK*256
    int*   offT  = histM + (size_t)NBLK * 256;       // 256*NBLK
    int*   btot  = offT + (size_t)NBLK * 256;        // 256
    int*   bbase = btot + 256;                       // 257
    float* h3    = (float*)hb;                       // N*10 fp32 (layer 3)

    // ---- CSR build (atomic-free counting sort; reused by all 3 layers) ----
    csr_hist<<<NBLK, 256, 0, stream>>>(ei, E, DPB, histM);
    csr_colscan<<<256, 256, 0, stream>>>(histM, NBLK, offT, btot);
    csr_basescan<<<1, 256, 0, stream>>>(btot, bbase);
    csr_pair_scatter<<<NBLK, 256, 0, stream>>>(ei, E, DPB, offT, NBLK, bbase, pairs);
    csr_fine<<<256, 256, 0, stream>>>(pairs, bbase, DPB, N, ptr, col);

    // ================= layer 1: 128 -> 8 heads x 16 =================
    gemm_tiled_bf<128, 128, 64, 64, 8><<<cdiv(N, 64), 256, 0, stream>>>(x, W1, hb, N);
    alpha_kernel<bf16, 8, 16><<<cdiv((long)N * 8, 256), 256, 0, stream>>>(hb, as1, ad1, asrc, adst, N);
    agg_ln_kernel<8, 16><<<N, 64, 0, stream>>>(ptr, col, asrc, adst, hb, b1, g1, be1, agg, N);

    // ================= layer 2: 128 -> 4 heads x 16 =================
    gemm_tiled_bf<128, 64, 128, 64, 8><<<cdiv(N, 128), 256, 0, stream>>>(agg, W2, hb, N);
    alpha_kernel<bf16, 4, 16><<<cdiv((long)N * 4, 256), 256, 0, stream>>>(hb, as2, ad2, asrc, adst, N);
    agg_ln_kernel<4, 16><<<N, 64, 0, stream>>>(ptr, col, asrc, adst, hb, b2, g2, be2, agg, N);

    // ================= layer 3: 64 -> 1 head x 10, mean(=identity) ==
    gemm_kernel<64, 10><<<cdiv((long)N * 10, 256), 256, 0, stream>>>(agg, W3, h3, N);
    alpha_kernel<float, 1, 10><<<cdiv(N, 256), 256, 0, stream>>>(h3, as3, ad3, asrc, adst, N);
    agg_csr_l3<<<cdiv(N, 4), 256, 0, stream>>>(ptr, col, asrc, adst, h3, agg, N);
    final_kernel<<<cdiv(N, 256), 256, 0, stream>>>(agg, b3, (float*)d_out, N);
}

// Round 10
// 465.113 us; speedup vs baseline: 45.2763x; 1.1412x over previous
//
#include <hip/hip_runtime.h>
#include <hip/hip_bf16.h>
#include <math.h>

typedef __hip_bfloat16 bf16;
typedef __bf16 bf16x8 __attribute__((ext_vector_type(8)));
typedef float floatx4 __attribute__((ext_vector_type(4)));

__device__ __forceinline__ unsigned short f2bu(float f) {
    bf16 b = __float2bfloat16(f);
    return __builtin_bit_cast(unsigned short, b);
}
__device__ __forceinline__ float ldf(const float* p, size_t i) { return p[i]; }
__device__ __forceinline__ float ldf(const bf16* p, size_t i) { return __bfloat162float(p[i]); }

// load PF bf16 features (packed) as floats
template<int PF>
__device__ __forceinline__ void ldbf(const bf16* p, float* v) {
    if constexpr (PF == 1) {
        unsigned short u = *reinterpret_cast<const unsigned short*>(p);
        v[0] = __uint_as_float(((unsigned)u) << 16);
    } else {
        unsigned u = *reinterpret_cast<const unsigned*>(p);
        v[0] = __uint_as_float(u << 16);
        v[1] = __uint_as_float(u & 0xffff0000u);
    }
}

// ================= MFMA GEMM: C[N,M] = X[N,128] @ W[128,M], bf16 out ========
// K=128 fits in LDS: one staging phase, one barrier, no K-loop global loads.
// Fragment layouts (m89/m91-verified): A[m=lane&15][k=quad*8+j],
// B[k=quad*8+j][n=lane&15], D[row=quad*4+reg][col=lane&15].
template<int M>
__global__ __launch_bounds__(256) void gemm_mfma(
    const float* __restrict__ X, const float* __restrict__ W,
    bf16* __restrict__ Hout, int N)
{
    constexpr int KP = 136;              // padded k-stride (bf16 elems)
    constexpr int NT = M / 16;           // 16-col tiles per wave
    __shared__ __align__(16) unsigned short Wt[M * KP];   // W^T: [n][k]
    __shared__ __align__(16) unsigned short As[64 * KP];  // A: [m][k]
    int tid = threadIdx.x;
    int r0 = blockIdx.x * 64;

    // stage W^T (bf16): global W[k][m] row-major, coalesced read
    for (int idx = tid; idx < 128 * M; idx += 256) {
        int k = idx / M, m = idx % M;
        Wt[m * KP + k] = f2bu(W[idx]);
    }
    // stage A tile (64 rows x 128 k), fp32 -> bf16
    for (int idx = tid; idx < 64 * 32; idx += 256) {
        int row = idx >> 5, c4 = (idx & 31) * 4;
        int grow = r0 + row;
        float4 v = make_float4(0.f, 0.f, 0.f, 0.f);
        if (grow < N)
            v = *reinterpret_cast<const float4*>(X + (size_t)grow * 128 + c4);
        unsigned short* a = &As[row * KP + c4];
        a[0] = f2bu(v.x); a[1] = f2bu(v.y); a[2] = f2bu(v.z); a[3] = f2bu(v.w);
    }
    __syncthreads();

    int w = tid >> 6, l = tid & 63, q = l >> 4, c = l & 15;
    floatx4 acc[NT];
    #pragma unroll
    for (int t = 0; t < NT; ++t) acc[t] = (floatx4){0.f, 0.f, 0.f, 0.f};

    #pragma unroll
    for (int kc = 0; kc < 4; ++kc) {
        bf16x8 a = *reinterpret_cast<const bf16x8*>(&As[(w * 16 + c) * KP + kc * 32 + q * 8]);
        #pragma unroll
        for (int t = 0; t < NT; ++t) {
            bf16x8 b = *reinterpret_cast<const bf16x8*>(&Wt[(t * 16 + c) * KP + kc * 32 + q * 8]);
            acc[t] = __builtin_amdgcn_mfma_f32_16x16x32_bf16(a, b, acc[t], 0, 0, 0);
        }
    }
    __syncthreads();
    // repack D into As ([64][M] bf16, stride KP) for coalesced stores
    #pragma unroll
    for (int t = 0; t < NT; ++t)
        #pragma unroll
        for (int r = 0; r < 4; ++r)
            As[(w * 16 + q * 4 + r) * KP + t * 16 + c] = f2bu(acc[t][r]);
    __syncthreads();
    for (int idx = tid; idx < 64 * (M / 8); idx += 256) {
        int row = idx / (M / 8), g = idx % (M / 8);
        int grow = r0 + row;
        if (grow < N)
            *reinterpret_cast<uint4*>(Hout + (size_t)grow * M + g * 8) =
                *reinterpret_cast<const uint4*>(&As[row * KP + g * 8]);
    }
}

// ---------------- alpha_src/alpha_dst: [N,H] = sum_f h[n,hd,f]*a[hd,f] ------
template<typename T, int H, int F>
__global__ __launch_bounds__(256) void alpha_kernel(
    const T* __restrict__ h, const float* __restrict__ av_src,
    const float* __restrict__ av_dst, float* __restrict__ asrc,
    float* __restrict__ adst, int N)
{
    int gid = blockIdx.x * 256 + threadIdx.x;
    if (gid >= N * H) return;
    int n = gid / H;
    int hd = gid - n * H;
    const T* hr = h + (size_t)n * (H * F) + hd * F;
    float s1 = 0.f, s2 = 0.f;
    #pragma unroll
    for (int f = 0; f < F; ++f) {
        float v = ldf(hr, f);
        s1 += v * av_src[hd * F + f];
        s2 += v * av_dst[hd * F + f];
    }
    asrc[gid] = s1;
    adst[gid] = s2;
}

// ============== atomic-free CSR build: counting sort by dst ==================
#define CSR_CH 4096

__global__ __launch_bounds__(256) void csr_hist(
    const int* __restrict__ ei, int E, int DPB, int* __restrict__ histM)
{
    __shared__ int cnt[256];
    int tid = threadIdx.x;
    cnt[tid] = 0;
    __syncthreads();
    int e0 = blockIdx.x * CSR_CH;
    int e1 = min(E, e0 + CSR_CH);
    for (int e = e0 + tid; e < e1; e += 256)
        atomicAdd(&cnt[ei[E + e] / DPB], 1);
    __syncthreads();
    histM[blockIdx.x * 256 + tid] = cnt[tid];
}

__global__ __launch_bounds__(256) void csr_colscan(
    const int* __restrict__ histM, int NBLK,
    int* __restrict__ offT, int* __restrict__ btot)
{
    __shared__ int sm[512];
    int b = blockIdx.x;
    int tid = threadIdx.x;
    int i0 = tid, i1 = tid + 256;
    sm[i0] = (i0 < NBLK) ? histM[i0 * 256 + b] : 0;
    sm[i1] = (i1 < NBLK) ? histM[i1 * 256 + b] : 0;
    __syncthreads();
    #pragma unroll
    for (int o = 1; o < 512; o <<= 1) {
        int t0 = (i0 >= o) ? sm[i0 - o] : 0;
        int t1 = (i1 >= o) ? sm[i1 - o] : 0;
        __syncthreads();
        sm[i0] += t0; sm[i1] += t1;
        __syncthreads();
    }
    if (i0 < NBLK) offT[b * NBLK + i0] = (i0 == 0) ? 0 : sm[i0 - 1];
    if (i1 < NBLK) offT[b * NBLK + i1] = sm[i1 - 1];
    if (tid == 0) btot[b] = sm[511];
}

__global__ __launch_bounds__(256) void csr_basescan(
    const int* __restrict__ btot, int* __restrict__ bbase)
{
    __shared__ int sm[256];
    int tid = threadIdx.x;
    int v = btot[tid];
    sm[tid] = v;
    __syncthreads();
    #pragma unroll
    for (int o = 1; o < 256; o <<= 1) {
        int t = (tid >= o) ? sm[tid - o] : 0;
        __syncthreads();
        sm[tid] += t;
        __syncthreads();
    }
    bbase[tid] = sm[tid] - v;            // exclusive
    if (tid == 255) bbase[256] = sm[255];
}

__global__ __launch_bounds__(256) void csr_pair_scatter(
    const int* __restrict__ ei, int E, int DPB,
    const int* __restrict__ offT, int NBLK, const int* __restrict__ bbase,
    int2* __restrict__ pairs)
{
    __shared__ int cnt[256];
    int tid = threadIdx.x;
    int blk = blockIdx.x;
    cnt[tid] = bbase[tid] + offT[tid * NBLK + blk];
    __syncthreads();
    int e0 = blk * CSR_CH;
    int e1 = min(E, e0 + CSR_CH);
    for (int e = e0 + tid; e < e1; e += 256) {
        int s = ei[e];
        int d = ei[E + e];
        int pos = atomicAdd(&cnt[d / DPB], 1);
        pairs[pos] = make_int2(s, d);
    }
}

__global__ __launch_bounds__(256) void csr_fine(
    const int2* __restrict__ pairs, const int* __restrict__ bbase,
    int DPB, int N, int* __restrict__ ptr, int* __restrict__ col)
{
    __shared__ int sm[512];
    __shared__ int off[512];
    int b = blockIdx.x;
    int tid = threadIdx.x;
    int base = bbase[b];
    int tot = bbase[b + 1] - base;
    int d0 = b * DPB;
    int i0 = tid, i1 = tid + 256;
    sm[i0] = 0; sm[i1] = 0;
    __syncthreads();
    for (int i = tid; i < tot; i += 256)
        atomicAdd(&sm[pairs[base + i].y - d0], 1);
    __syncthreads();
    #pragma unroll
    for (int o = 1; o < 512; o <<= 1) {
        int t0 = (i0 >= o) ? sm[i0 - o] : 0;
        int t1 = (i1 >= o) ? sm[i1 - o] : 0;
        __syncthreads();
        sm[i0] += t0; sm[i1] += t1;
        __syncthreads();
    }
    off[i0] = base + ((i0 == 0) ? 0 : sm[i0 - 1]);
    off[i1] = base + sm[i1 - 1];
    if (i0 < DPB && d0 + i0 < N) ptr[d0 + i0] = base + sm[i0];
    if (i1 < DPB && d0 + i1 < N) ptr[d0 + i1] = base + sm[i1];
    __syncthreads();
    for (int i = tid; i < tot; i += 256) {
        int2 p = pairs[base + i];
        int pos = atomicAdd(&off[p.y - d0], 1);
        col[pos] = p.x;
    }
}

// ------- CSR agg + bias + LN + ELU fused: one WAVE per dst node -------------
template<int H, int F>
__global__ __launch_bounds__(64) void agg_ln_kernel(
    const int* __restrict__ ptr, const int* __restrict__ col,
    const float* __restrict__ asrc, const float* __restrict__ adst,
    const bf16* __restrict__ hb, const float* __restrict__ bias,
    const float* __restrict__ g, const float* __restrict__ be,
    float* __restrict__ out, int N)
{
    constexpr int M = H * F;
    constexpr int PF = M / 64;
    int d = blockIdx.x;
    int lane = threadIdx.x;
    int f0 = lane * PF;
    int hd = f0 / F;
    int start = (d == 0) ? 0 : ptr[d - 1];
    int end = ptr[d];
    float adst_h = adst[d * H + hd];

    float ac0[PF], ac1[PF], ac2[PF], ac3[PF];
    float dn0, dn1 = 0.f, dn2 = 0.f, dn3 = 0.f;
    #pragma unroll
    for (int p = 0; p < PF; ++p) { ac1[p] = 0.f; ac2[p] = 0.f; ac3[p] = 0.f; }

    { // self loop -> chain 0
        float lg = asrc[d * H + hd] + adst_h;
        lg = lg > 0.f ? lg : 0.2f * lg;
        float w = __expf(lg);
        float v[PF];
        ldbf<PF>(hb + (size_t)d * M + f0, v);
        #pragma unroll
        for (int p = 0; p < PF; ++p) ac0[p] = w * v[p];
        dn0 = w;
    }

    int e = start;
    for (; e + 4 <= end; e += 4) {
        int s0 = col[e + 0], s1 = col[e + 1], s2 = col[e + 2], s3 = col[e + 3];
        float l0 = asrc[s0 * H + hd];
        float l1 = asrc[s1 * H + hd];
        float l2 = asrc[s2 * H + hd];
        float l3 = asrc[s3 * H + hd];
        float v0[PF], v1[PF], v2[PF], v3[PF];
        ldbf<PF>(hb + (size_t)s0 * M + f0, v0);
        ldbf<PF>(hb + (size_t)s1 * M + f0, v1);
        ldbf<PF>(hb + (size_t)s2 * M + f0, v2);
        ldbf<PF>(hb + (size_t)s3 * M + f0, v3);
        l0 += adst_h; l0 = l0 > 0.f ? l0 : 0.2f * l0; float w0 = __expf(l0);
        l1 += adst_h; l1 = l1 > 0.f ? l1 : 0.2f * l1; float w1 = __expf(l1);
        l2 += adst_h; l2 = l2 > 0.f ? l2 : 0.2f * l2; float w2 = __expf(l2);
        l3 += adst_h; l3 = l3 > 0.f ? l3 : 0.2f * l3; float w3 = __expf(l3);
        #pragma unroll
        for (int p = 0; p < PF; ++p) {
            ac0[p] += w0 * v0[p];
            ac1[p] += w1 * v1[p];
            ac2[p] += w2 * v2[p];
            ac3[p] += w3 * v3[p];
        }
        dn0 += w0; dn1 += w1; dn2 += w2; dn3 += w3;
    }
    for (; e < end; ++e) {
        int s = col[e];
        float lg = asrc[s * H + hd] + adst_h;
        lg = lg > 0.f ? lg : 0.2f * lg;
        float w = __expf(lg);
        float v[PF];
        ldbf<PF>(hb + (size_t)s * M + f0, v);
        #pragma unroll
        for (int p = 0; p < PF; ++p) ac0[p] += w * v[p];
        dn0 += w;
    }

    float den = dn0 + dn1 + dn2 + dn3;
    float rden = 1.f / (den + 1e-16f);
    float o[PF];
    float sm1 = 0.f, sm2 = 0.f;
    #pragma unroll
    for (int p = 0; p < PF; ++p) {
        o[p] = (ac0[p] + ac1[p] + ac2[p] + ac3[p]) * rden + bias[f0 + p];
        sm1 += o[p];
        sm2 += o[p] * o[p];
    }
    #pragma unroll
    for (int off = 32; off >= 1; off >>= 1) {
        sm1 += __shfl_xor(sm1, off, 64);
        sm2 += __shfl_xor(sm2, off, 64);
    }
    float mu = sm1 * (1.f / M);
    float var = sm2 * (1.f / M) - mu * mu;
    float inv = rsqrtf(var + 1e-5f);
    float y[PF];
    #pragma unroll
    for (int p = 0; p < PF; ++p) {
        float t = (o[p] - mu) * inv * g[f0 + p] + be[f0 + p];
        y[p] = t > 0.f ? t : expm1f(t);
    }
    if constexpr (PF == 2) {
        *reinterpret_cast<float2*>(out + (size_t)d * M + f0) = make_float2(y[0], y[1]);
    } else {
        out[(size_t)d * M + f0] = y[0];
    }
}

// ------- layer 3 GEMM (64->10) + alpha fused: one thread per node -----------
__global__ __launch_bounds__(256) void gemm3_alpha(
    const float* __restrict__ X, const float* __restrict__ W3,
    const float* __restrict__ av_src, const float* __restrict__ av_dst,
    float* __restrict__ h3, float* __restrict__ asrc, float* __restrict__ adst,
    int N)
{
    __shared__ float Wl[640];
    int tid = threadIdx.x;
    for (int i = tid; i < 640; i += 256) Wl[i] = W3[i];   // FIX: full staging
    __syncthreads();
    int n = blockIdx.x * 256 + tid;
    if (n >= N) return;
    float h[10];
    #pragma unroll
    for (int j = 0; j < 10; ++j) h[j] = 0.f;
    const float* xr = X + (size_t)n * 64;
    for (int k4 = 0; k4 < 16; ++k4) {
        float4 xv = *reinterpret_cast<const float4*>(xr + k4 * 4);
        #pragma unroll
        for (int j = 0; j < 10; ++j) {
            h[j] += xv.x * Wl[(k4 * 4 + 0) * 10 + j];
            h[j] += xv.y * Wl[(k4 * 4 + 1) * 10 + j];
            h[j] += xv.z * Wl[(k4 * 4 + 2) * 10 + j];
            h[j] += xv.w * Wl[(k4 * 4 + 3) * 10 + j];
        }
    }
    float s1 = 0.f, s2 = 0.f;
    #pragma unroll
    for (int j = 0; j < 10; ++j) {
        h3[(size_t)n * 10 + j] = h[j];
        s1 += h[j] * av_src[j];
        s2 += h[j] * av_dst[j];
    }
    asrc[n] = s1;
    adst[n] = s2;
}

// --- layer-3 agg + bias + log_softmax fused: one wave per dst, write d_out --
__global__ __launch_bounds__(256) void agg_l3_final(
    const int* __restrict__ ptr, const int* __restrict__ col,
    const float* __restrict__ asrc, const float* __restrict__ adst,
    const float* __restrict__ h, const float* __restrict__ b3,
    float* __restrict__ out, int N)
{
    int wave = threadIdx.x >> 6;
    int lane = threadIdx.x & 63;
    int d = blockIdx.x * 4 + wave;
    if (d >= N) return;
    int start = (d == 0) ? 0 : ptr[d - 1];
    int end = ptr[d];
    float adst_d = adst[d];
    float lg = asrc[d] + adst_d;
    lg = lg > 0.f ? lg : 0.2f * lg;
    float w = __expf(lg);
    bool act = lane < 10;
    float a0 = act ? w * h[(size_t)d * 10 + lane] : 0.f;
    float a1 = 0.f, a2 = 0.f, a3 = 0.f;
    float d0 = w, d1 = 0.f, d2 = 0.f, d3 = 0.f;
    int e = start;
    for (; e + 4 <= end; e += 4) {
        int s0 = col[e + 0], s1 = col[e + 1], s2 = col[e + 2], s3 = col[e + 3];
        float l0 = asrc[s0], l1 = asrc[s1], l2 = asrc[s2], l3 = asrc[s3];
        float v0 = act ? h[(size_t)s0 * 10 + lane] : 0.f;
        float v1 = act ? h[(size_t)s1 * 10 + lane] : 0.f;
        float v2 = act ? h[(size_t)s2 * 10 + lane] : 0.f;
        float v3 = act ? h[(size_t)s3 * 10 + lane] : 0.f;
        l0 += adst_d; l0 = l0 > 0.f ? l0 : 0.2f * l0; float w0 = __expf(l0);
        l1 += adst_d; l1 = l1 > 0.f ? l1 : 0.2f * l1; float w1 = __expf(l1);
        l2 += adst_d; l2 = l2 > 0.f ? l2 : 0.2f * l2; float w2 = __expf(l2);
        l3 += adst_d; l3 = l3 > 0.f ? l3 : 0.2f * l3; float w3 = __expf(l3);
        a0 += w0 * v0; a1 += w1 * v1; a2 += w2 * v2; a3 += w3 * v3;
        d0 += w0; d1 += w1; d2 += w2; d3 += w3;
    }
    for (; e < end; ++e) {
        int s = col[e];
        float l = asrc[s] + adst_d;
        l = l > 0.f ? l : 0.2f * l;
        float ww = __expf(l);
        if (act) a0 += ww * h[(size_t)s * 10 + lane];
        d0 += ww;
    }
    float den = d0 + d1 + d2 + d3;
    float v = (a0 + a1 + a2 + a3) / (den + 1e-16f);
    // fused +bias, log_softmax across the 10 values (lanes 0..9 of each 16-group)
    float lv = act ? v + b3[lane] : -1e30f;
    float mx = lv;
    #pragma unroll
    for (int off = 1; off < 16; off <<= 1) mx = fmaxf(mx, __shfl_xor(mx, off, 16));
    float ev = act ? __expf(lv - mx) : 0.f;
    float se = ev;
    #pragma unroll
    for (int off = 1; off < 16; off <<= 1) se += __shfl_xor(se, off, 16);
    float ls = mx + logf(se);
    if (act) out[(size_t)d * 10 + lane] = lv - ls;
}

static inline int cdiv(long a, long b) { return (int)((a + b - 1) / b); }

extern "C" void kernel_launch(void* const* d_in, const int* in_sizes, int n_in,
                              void* d_out, int out_size, void* d_ws, size_t ws_size,
                              hipStream_t stream)
{
    const float* x   = (const float*)d_in[0];
    const int*   ei  = (const int*)d_in[1];
    const float* W1  = (const float*)d_in[2];
    const float* as1 = (const float*)d_in[3];
    const float* ad1 = (const float*)d_in[4];
    const float* b1  = (const float*)d_in[5];
    const float* g1  = (const float*)d_in[6];
    const float* be1 = (const float*)d_in[7];
    const float* W2  = (const float*)d_in[8];
    const float* as2 = (const float*)d_in[9];
    const float* ad2 = (const float*)d_in[10];
    const float* b2  = (const float*)d_in[11];
    const float* g2  = (const float*)d_in[12];
    const float* be2 = (const float*)d_in[13];
    const float* W3  = (const float*)d_in[14];
    const float* as3 = (const float*)d_in[15];
    const float* ad3 = (const float*)d_in[16];
    const float* b3  = (const float*)d_in[17];

    const int N = in_sizes[0] / 128;
    const int E = in_sizes[1] / 2;

    const int DPB  = cdiv(N, 256);         // dsts per bucket
    const int NBLK = cdiv(E, CSR_CH);      // edge chunks (must be <= 512)

    bf16*  hb    = (bf16*)d_ws;                      // N*128 bf16
    float* agg   = (float*)(hb + (size_t)N * 128);   // N*128 fp32
    float* asrc  = agg + (size_t)N * 128;            // N*8
    float* adst  = asrc + (size_t)N * 8;             // N*8
    int2*  pairs = (int2*)(adst + (size_t)N * 8);    // E pairs
    int*   col   = (int*)(pairs + E);                // E
    int*   ptr   = col + E;                          // N+1
    int*   histM = ptr + (N + 1);                    // NBLK*256
    int*   offT  = histM + (size_t)NBLK * 256;       // 256*NBLK
    int*   btot  = offT + (size_t)NBLK * 256;        // 256
    int*   bbase = btot + 256;                       // 257
    float* h3    = (float*)hb;                       // N*10 fp32 (layer 3)

    // ---- CSR build (atomic-free counting sort; reused by all 3 layers) ----
    csr_hist<<<NBLK, 256, 0, stream>>>(ei, E, DPB, histM);
    csr_colscan<<<256, 256, 0, stream>>>(histM, NBLK, offT, btot);
    csr_basescan<<<1, 256, 0, stream>>>(btot, bbase);
    csr_pair_scatter<<<NBLK, 256, 0, stream>>>(ei, E, DPB, offT, NBLK, bbase, pairs);
    csr_fine<<<256, 256, 0, stream>>>(pairs, bbase, DPB, N, ptr, col);

    // ================= layer 1: 128 -> 8 heads x 16 =================
    gemm_mfma<128><<<cdiv(N, 64), 256, 0, stream>>>(x, W1, hb, N);
    alpha_kernel<bf16, 8, 16><<<cdiv((long)N * 8, 256), 256, 0, stream>>>(hb, as1, ad1, asrc, adst, N);
    agg_ln_kernel<8, 16><<<N, 64, 0, stream>>>(ptr, col, asrc, adst, hb, b1, g1, be1, agg, N);

    // ================= layer 2: 128 -> 4 heads x 16 =================
    gemm_mfma<64><<<cdiv(N, 64), 256, 0, stream>>>(agg, W2, hb, N);
    alpha_kernel<bf16, 4, 16><<<cdiv((long)N * 4, 256), 256, 0, stream>>>(hb, as2, ad2, asrc, adst, N);
    agg_ln_kernel<4, 16><<<N, 64, 0, stream>>>(ptr, col, asrc, adst, hb, b2, g2, be2, agg, N);

    // ================= layer 3: 64 -> 1 head x 10, mean(=identity) ==
    gemm3_alpha<<<cdiv(N, 256), 256, 0, stream>>>(agg, W3, as3, ad3, h3, asrc, adst, N);
    agg_l3_final<<<cdiv(N, 4), 256, 0, stream>>>(ptr, col, asrc, adst, h3, b3, (float*)d_out, N);
}